// Round 2
// baseline (849.080 us; speedup 1.0000x reference)
//
#include <hip/hip_runtime.h>
#include <hip/hip_bf16.h>
#include <stdint.h>
#include <stddef.h>

#define R_ 64
#define C_ 256
#define E_ 768
#define H_ 12
#define F_ 3072
#define D_ 64
#define NT_ (R_*C_)   // 16384 tokens

typedef float f32x4 __attribute__((ext_vector_type(4)));
typedef __bf16 bf16x8 __attribute__((ext_vector_type(8)));
typedef unsigned short us4 __attribute__((ext_vector_type(4)));

typedef __attribute__((address_space(3))) uint32_t lds_u32;
typedef __attribute__((address_space(1))) uint32_t glb_u32;

__device__ __forceinline__ void gld16(const uint16_t* g, uint16_t* l) {
  // async global->LDS, 16B per lane; LDS dest must be wave-uniform base + lane*16
  __builtin_amdgcn_global_load_lds((const glb_u32*)g, (lds_u32*)l, 16, 0, 0);
}

__device__ __forceinline__ uint16_t f2b(float f) { // fp32 -> bf16 bits, RNE
  uint32_t x = __float_as_uint(f);
  return (uint16_t)((x + 0x7fffu + ((x >> 16) & 1u)) >> 16);
}

// ---------------------------------------------------------------- GEMM
// C(MxN) = A(MxK, bf16 row-major) * B^T (B is NxK bf16 row-major), + epilogue.
// 128x128 tile, BK=32, 256 threads (4 waves, each 64x64 via 4x4 frags of 16x16x32).
enum { EP_F32B = 0, EP_PERMQK = 1, EP_VROW = 2, EP_VCOL = 3, EP_GELU = 4, EP_AW = 5, EP_CTX = 6 };

template<int EP>
__global__ __launch_bounds__(256)
void gemm_bt(const uint16_t* __restrict__ A, const uint16_t* __restrict__ B,
             const float* __restrict__ bias, void* __restrict__ out,
             int M, int N, int K, long sAz, long sBz, float scale)
{
  __shared__ uint16_t As[128 * 32];
  __shared__ uint16_t Bs[128 * 32];
  const int tid  = threadIdx.x;
  const int wave = tid >> 6, lane = tid & 63;
  const int z = blockIdx.z;
  const long bm = (long)blockIdx.y * 128;
  const long bn = (long)blockIdx.x * 128;
  const uint16_t* Ab = A + (long)z * sAz + bm * (long)K;
  const uint16_t* Bb = B + (long)z * sBz + bn * (long)K;
  const int wr = (wave >> 1) * 64;
  const int wc = (wave & 1) * 64;
  const int lr = lane & 15;
  const int lq = lane >> 4;

  // staging map: t in [0,512): row = t>>2, k-offset = (t&3)*8  (16B per slot)
  const int t0 = tid, t1 = tid + 256;
  const int ar0 = t0 >> 2, ac0 = (t0 & 3) * 8;
  const int ar1 = t1 >> 2, ac1 = (t1 & 3) * 8;

  f32x4 acc[4][4];
#pragma unroll
  for (int i = 0; i < 4; ++i)
#pragma unroll
    for (int j = 0; j < 4; ++j) acc[i][j] = (f32x4){0.f, 0.f, 0.f, 0.f};

  for (int kt = 0; kt < K; kt += 32) {
    __syncthreads();
    gld16(Ab + (long)ar0 * K + kt + ac0, &As[t0 * 8]);
    gld16(Ab + (long)ar1 * K + kt + ac1, &As[t1 * 8]);
    gld16(Bb + (long)ar0 * K + kt + ac0, &Bs[t0 * 8]);
    gld16(Bb + (long)ar1 * K + kt + ac1, &Bs[t1 * 8]);
    __syncthreads();   // drains vmcnt before any wave reads LDS

    bf16x8 af[4], bfm[4];
#pragma unroll
    for (int i = 0; i < 4; ++i) {
      af[i]  = *(const bf16x8*)&As[(wr + i * 16 + lr) * 32 + lq * 8];
      bfm[i] = *(const bf16x8*)&Bs[(wc + i * 16 + lr) * 32 + lq * 8];
    }
#pragma unroll
    for (int mi = 0; mi < 4; ++mi)
#pragma unroll
      for (int ni = 0; ni < 4; ++ni)
        acc[mi][ni] = __builtin_amdgcn_mfma_f32_16x16x32_bf16(af[mi], bfm[ni], acc[mi][ni], 0, 0, 0);
  }

  // epilogue: C/D layout col = lane&15, row = (lane>>4)*4 + reg
#pragma unroll
  for (int mi = 0; mi < 4; ++mi) {
#pragma unroll
    for (int ni = 0; ni < 4; ++ni) {
#pragma unroll
      for (int r = 0; r < 4; ++r) {
        const long row = bm + wr + mi * 16 + lq * 4 + r;
        const long col = bn + wc + ni * 16 + lr;
        const float v = acc[mi][ni][r];
        if constexpr (EP == EP_F32B) {
          ((float*)out)[row * N + col] = v + bias[col];
        } else if constexpr (EP == EP_PERMQK) {
          // token m=(mhi,mlo); store q_t[h][mlo][mhi][d]  (layout H,C,R,D)
          const float val = (v + bias[col]) * scale;
          const long h = col >> 6, d = col & 63, mlo = row & 255, mhi = row >> 8;
          ((uint16_t*)out)[((h * C_ + mlo) * R_ + mhi) * D_ + d] = f2b(val);
        } else if constexpr (EP == EP_VROW) {
          // v_tt[h][(r*D+d)][j]  (layout H, R*D, C); m=(r,j)
          const float val = v + bias[col];
          const long h = col >> 6, d = col & 63, mlo = row & 255, mhi = row >> 8;
          ((uint16_t*)out)[((h * R_ + mhi) * D_ + d) * C_ + mlo] = f2b(val);
        } else if constexpr (EP == EP_VCOL) {
          // v2_t[h][c][d][j]  (layout H,C,D,R); m=(j,c)
          const float val = v + bias[col];
          const long h = col >> 6, d = col & 63, mlo = row & 255, mhi = row >> 8;
          ((uint16_t*)out)[((h * C_ + mlo) * D_ + d) * R_ + mhi] = f2b(val);
        } else if constexpr (EP == EP_GELU) {
          const float t = v + bias[col];
          const float u = 0.7978845608028654f * (t + 0.044715f * t * t * t);
          const float e = __expf(2.f * u);
          const float th = 1.f - 2.f / (e + 1.f);   // tanh(u), inf-safe
          ((uint16_t*)out)[row * N + col] = f2b(0.5f * t * (1.f + th));
        } else if constexpr (EP == EP_AW) {
          ((float*)out)[((long)z * M + row) * N + col] = v;
        } else { // EP_CTX: out[( (r)*C + i )*E + h*64 + d], col=(r,d), row=i, z=h
          ((uint16_t*)out)[((col >> 6) * C_ + row) * E_ + (long)z * 64 + (col & 63)] = f2b(v);
        }
      }
    }
  }
}

// ---------------------------------------------------------------- LayerNorm (fp32 in -> bf16 out)
__global__ __launch_bounds__(256)
void ln_k(const float* __restrict__ x, const float* __restrict__ s, const float* __restrict__ b,
          uint16_t* __restrict__ out)
{
  const int wave = threadIdx.x >> 6, lane = threadIdx.x & 63;
  const long row = (long)blockIdx.x * 4 + wave;
  const float* xr = x + row * E_;
  f32x4 v[3];
  float sum = 0.f, sq = 0.f;
#pragma unroll
  for (int i = 0; i < 3; ++i) {
    v[i] = *(const f32x4*)(xr + (i * 64 + lane) * 4);
#pragma unroll
    for (int j = 0; j < 4; ++j) { sum += v[i][j]; sq += v[i][j] * v[i][j]; }
  }
#pragma unroll
  for (int m = 1; m < 64; m <<= 1) { sum += __shfl_xor(sum, m); sq += __shfl_xor(sq, m); }
  const float mu = sum * (1.f / E_);
  const float var = sq * (1.f / E_) - mu * mu;
  const float rs = rsqrtf(var + 1e-6f);
  uint16_t* orow = out + row * E_;
#pragma unroll
  for (int i = 0; i < 3; ++i) {
    const int e0 = (i * 64 + lane) * 4;
    us4 o;
#pragma unroll
    for (int j = 0; j < 4; ++j) o[j] = f2b((v[i][j] - mu) * rs * s[e0 + j] + b[e0 + j]);
    *(us4*)(orow + e0) = o;
  }
}

// ---------------------------------------------------------------- softmax over 256 (fp32 -> bf16)
__global__ __launch_bounds__(256)
void softmax_k(const float* __restrict__ aw, uint16_t* __restrict__ ap)
{
  const int wave = threadIdx.x >> 6, lane = threadIdx.x & 63;
  const long row = (long)blockIdx.x * 4 + wave;
  const float* r = aw + row * C_;
  f32x4 v = *(const f32x4*)(r + lane * 4);
  float m = fmaxf(fmaxf(v[0], v[1]), fmaxf(v[2], v[3]));
#pragma unroll
  for (int k = 1; k < 64; k <<= 1) m = fmaxf(m, __shfl_xor(m, k));
  f32x4 e; float s = 0.f;
#pragma unroll
  for (int j = 0; j < 4; ++j) { e[j] = __expf(v[j] - m); s += e[j]; }
#pragma unroll
  for (int k = 1; k < 64; k <<= 1) s += __shfl_xor(s, k);
  const float inv = 1.f / s;
  us4 o;
#pragma unroll
  for (int j = 0; j < 4; ++j) o[j] = f2b(e[j] * inv);
  *(us4*)(ap + row * C_ + lane * 4) = o;
}

// ---------------------------------------------------------------- weight transpose + fp32->bf16
// in: (K,N) fp32 row-major; out: (N,K) bf16 row-major
__global__ __launch_bounds__(256)
void tcvt(const float* __restrict__ in, uint16_t* __restrict__ out, int K, int N)
{
  __shared__ float t[32][33];
  const int tx = threadIdx.x, ty = threadIdx.y;   // block (32,8)
  const long k0 = (long)blockIdx.y * 32, n0 = (long)blockIdx.x * 32;
  for (int i = ty; i < 32; i += 8) t[i][tx] = in[(k0 + i) * N + n0 + tx];
  __syncthreads();
  for (int i = ty; i < 32; i += 8) out[(n0 + i) * K + k0 + tx] = f2b(t[tx][i]);
}

// ---------------------------------------------------------------- fused column attention
// one wave per (h,c): S=Q K^T (64x64), row softmax, ctx = P V. q,k: (H,C,R,D); v: (H,C,D,R)
__global__ __launch_bounds__(64)
void colattn(const uint16_t* __restrict__ q, const uint16_t* __restrict__ k,
             const uint16_t* __restrict__ v, uint16_t* __restrict__ ctx)
{
  __shared__ uint16_t Qs[64 * 64];   // reused for P after S is consumed
  __shared__ uint16_t Ks[64 * 64];
  __shared__ uint16_t Vs[64 * 64];
  const int hc = blockIdx.x;
  const int h = hc >> 8, c = hc & 255;
  const int lane = threadIdx.x;
  const uint16_t* qb = q + (long)hc * (R_ * D_);
  const uint16_t* kb = k + (long)hc * (R_ * D_);
  const uint16_t* vb = v + (long)hc * (D_ * R_);
#pragma unroll
  for (int it = 0; it < 8; ++it) {
    const int o = (it * 64 + lane) * 8;
    gld16(qb + o, &Qs[o]);
    gld16(kb + o, &Ks[o]);
    gld16(vb + o, &Vs[o]);
  }
  asm volatile("s_waitcnt vmcnt(0)" ::: "memory");
  __builtin_amdgcn_sched_barrier(0);

  const int lr = lane & 15, lq = lane >> 4;
  f32x4 acc[4][4];
#pragma unroll
  for (int i = 0; i < 4; ++i)
#pragma unroll
    for (int j = 0; j < 4; ++j) acc[i][j] = (f32x4){0.f, 0.f, 0.f, 0.f};

#pragma unroll
  for (int kt = 0; kt < 2; ++kt) {
    bf16x8 af[4], bfm[4];
#pragma unroll
    for (int i = 0; i < 4; ++i) {
      af[i]  = *(const bf16x8*)&Qs[(i * 16 + lr) * 64 + kt * 32 + lq * 8];
      bfm[i] = *(const bf16x8*)&Ks[(i * 16 + lr) * 64 + kt * 32 + lq * 8];
    }
#pragma unroll
    for (int mi = 0; mi < 4; ++mi)
#pragma unroll
      for (int ni = 0; ni < 4; ++ni)
        acc[mi][ni] = __builtin_amdgcn_mfma_f32_16x16x32_bf16(af[mi], bfm[ni], acc[mi][ni], 0, 0, 0);
  }

  // row softmax: row i = mi*16+lq*4+r spans cols ni*16+lr across the 16-lane group
#pragma unroll
  for (int mi = 0; mi < 4; ++mi) {
#pragma unroll
    for (int r = 0; r < 4; ++r) {
      float mx = fmaxf(fmaxf(acc[mi][0][r], acc[mi][1][r]), fmaxf(acc[mi][2][r], acc[mi][3][r]));
#pragma unroll
      for (int s = 1; s < 16; s <<= 1) mx = fmaxf(mx, __shfl_xor(mx, s));
      float e0 = __expf(acc[mi][0][r] - mx), e1 = __expf(acc[mi][1][r] - mx);
      float e2 = __expf(acc[mi][2][r] - mx), e3 = __expf(acc[mi][3][r] - mx);
      float sum = e0 + e1 + e2 + e3;
#pragma unroll
      for (int s = 1; s < 16; s <<= 1) sum += __shfl_xor(sum, s);
      const float inv = 1.f / sum;
      const int i = mi * 16 + lq * 4 + r;
      Qs[i * 64 +  0 + lr] = f2b(e0 * inv);
      Qs[i * 64 + 16 + lr] = f2b(e1 * inv);
      Qs[i * 64 + 32 + lr] = f2b(e2 * inv);
      Qs[i * 64 + 48 + lr] = f2b(e3 * inv);
    }
  }
  __syncthreads();

  f32x4 o_[4][4];
#pragma unroll
  for (int i = 0; i < 4; ++i)
#pragma unroll
    for (int j = 0; j < 4; ++j) o_[i][j] = (f32x4){0.f, 0.f, 0.f, 0.f};

#pragma unroll
  for (int kt = 0; kt < 2; ++kt) {
    bf16x8 pa[4], vv[4];
#pragma unroll
    for (int i = 0; i < 4; ++i) {
      pa[i] = *(const bf16x8*)&Qs[(i * 16 + lr) * 64 + kt * 32 + lq * 8];
      vv[i] = *(const bf16x8*)&Vs[(i * 16 + lr) * 64 + kt * 32 + lq * 8];
    }
#pragma unroll
    for (int mi = 0; mi < 4; ++mi)
#pragma unroll
      for (int ni = 0; ni < 4; ++ni)
        o_[mi][ni] = __builtin_amdgcn_mfma_f32_16x16x32_bf16(pa[mi], vv[ni], o_[mi][ni], 0, 0, 0);
  }

#pragma unroll
  for (int mi = 0; mi < 4; ++mi)
#pragma unroll
    for (int ni = 0; ni < 4; ++ni)
#pragma unroll
      for (int r = 0; r < 4; ++r) {
        const int i = mi * 16 + lq * 4 + r;
        const int d = ni * 16 + lr;
        ctx[((long)i * C_ + c) * E_ + h * 64 + d] = f2b(o_[mi][ni][r]);
      }
}

// ---------------------------------------------------------------- host launch
extern "C" void kernel_launch(void* const* d_in, const int* in_sizes, int n_in,
                              void* d_out, int out_size, void* d_ws, size_t ws_size,
                              hipStream_t stream)
{
  (void)in_sizes; (void)n_in; (void)out_size; (void)ws_size;
  const float* x     = (const float*)d_in[0];
  const float* ln1_s = (const float*)d_in[1];
  const float* ln1_b = (const float*)d_in[2];
  const float* r_wq  = (const float*)d_in[3];
  const float* r_bq  = (const float*)d_in[4];
  const float* r_wk  = (const float*)d_in[5];
  const float* r_bk  = (const float*)d_in[6];
  const float* r_wv  = (const float*)d_in[7];
  const float* r_bv  = (const float*)d_in[8];
  const float* r_wo  = (const float*)d_in[9];
  const float* r_bo  = (const float*)d_in[10];
  const float* ln2_s = (const float*)d_in[11];
  const float* ln2_b = (const float*)d_in[12];
  const float* c_wq  = (const float*)d_in[13];
  const float* c_bq  = (const float*)d_in[14];
  const float* c_wk  = (const float*)d_in[15];
  const float* c_bk  = (const float*)d_in[16];
  const float* c_wv  = (const float*)d_in[17];
  const float* c_bv  = (const float*)d_in[18];
  const float* c_wo  = (const float*)d_in[19];
  const float* c_bo  = (const float*)d_in[20];
  const float* ln3_s = (const float*)d_in[21];
  const float* ln3_b = (const float*)d_in[22];
  const float* f_w1  = (const float*)d_in[23];
  const float* f_b1  = (const float*)d_in[24];
  const float* f_w2  = (const float*)d_in[25];
  const float* f_b2  = (const float*)d_in[26];

  // ---------- workspace layout (≈139.5 MiB peak; aliasing commented) ----------
  uint8_t* p = (uint8_t*)d_ws;
  auto take = [&p](size_t n) { uint8_t* r = p; p += (n + 255) & ~(size_t)255; return r; };

  uint16_t* rwqT = (uint16_t*)take((size_t)E_ * E_ * 2);
  uint16_t* rwkT = (uint16_t*)take((size_t)E_ * E_ * 2);
  uint16_t* rwvT = (uint16_t*)take((size_t)E_ * E_ * 2);
  uint16_t* rwoT = (uint16_t*)take((size_t)E_ * E_ * 2);
  uint16_t* cwqT = (uint16_t*)take((size_t)E_ * E_ * 2);
  uint16_t* cwkT = (uint16_t*)take((size_t)E_ * E_ * 2);
  uint16_t* cwvT = (uint16_t*)take((size_t)E_ * E_ * 2);
  uint16_t* cwoT = (uint16_t*)take((size_t)E_ * E_ * 2);
  uint16_t* w1T  = (uint16_t*)take((size_t)E_ * F_ * 2);   // (F,E)
  uint16_t* w2T  = (uint16_t*)take((size_t)F_ * E_ * 2);   // (E,F)
  uint16_t* hb   = (uint16_t*)take((size_t)NT_ * E_ * 2);
  // q/k/v/ctx region: 4 x 25.166 MB = 100.66 MB; g (NT*F bf16, stage 3) aliases it.
  uint16_t* qT   = (uint16_t*)take((size_t)H_ * C_ * R_ * D_ * 2);
  uint16_t* kT   = (uint16_t*)take((size_t)H_ * C_ * R_ * D_ * 2);
  uint16_t* vT   = (uint16_t*)take((size_t)H_ * C_ * R_ * D_ * 2);
  uint16_t* ctxb = (uint16_t*)take((size_t)NT_ * E_ * 2);
  uint16_t* apb  = (uint16_t*)take((size_t)H_ * C_ * C_ * 2);
  uint16_t* g    = qT;            // alias: stage-3 FFN hidden over dead q/k/v/ctx
  float*    awb  = (float*)ctxb;  // alias: aw (fp32, 3.1 MB) dead before ctxb written
  float*    x1   = (float*)d_out; // alias: inter-stage fp32 activation in output buf

  const dim3 tb32(32, 8);
  const dim3 gEE(E_ / 32, E_ / 32);
  tcvt<<<gEE, tb32, 0, stream>>>(r_wq, rwqT, E_, E_);
  tcvt<<<gEE, tb32, 0, stream>>>(r_wk, rwkT, E_, E_);
  tcvt<<<gEE, tb32, 0, stream>>>(r_wv, rwvT, E_, E_);
  tcvt<<<gEE, tb32, 0, stream>>>(r_wo, rwoT, E_, E_);
  tcvt<<<gEE, tb32, 0, stream>>>(c_wq, cwqT, E_, E_);
  tcvt<<<gEE, tb32, 0, stream>>>(c_wk, cwkT, E_, E_);
  tcvt<<<gEE, tb32, 0, stream>>>(c_wv, cwvT, E_, E_);
  tcvt<<<gEE, tb32, 0, stream>>>(c_wo, cwoT, E_, E_);
  tcvt<<<dim3(F_ / 32, E_ / 32), tb32, 0, stream>>>(f_w1, w1T, E_, F_);  // -> (F,E)
  tcvt<<<dim3(E_ / 32, F_ / 32), tb32, 0, stream>>>(f_w2, w2T, F_, E_);  // -> (E,F)

  const dim3 gProj(E_ / 128, NT_ / 128, 1);

  // ---- stage 1: tied-row attention ----
  ln_k<<<NT_ / 4, 256, 0, stream>>>(x, ln1_s, ln1_b, hb);
  gemm_bt<EP_PERMQK><<<gProj, 256, 0, stream>>>(hb, rwqT, r_bq, qT, NT_, E_, E_, 0, 0, 0.015625f); // D^-.5/sqrt(R)
  gemm_bt<EP_PERMQK><<<gProj, 256, 0, stream>>>(hb, rwkT, r_bk, kT, NT_, E_, E_, 0, 0, 1.f);
  gemm_bt<EP_VROW ><<<gProj, 256, 0, stream>>>(hb, rwvT, r_bv, vT, NT_, E_, E_, 0, 0, 1.f);
  gemm_bt<EP_AW><<<dim3(C_ / 128, C_ / 128, H_), 256, 0, stream>>>(
      qT, kT, nullptr, awb, C_, C_, R_ * D_, (long)C_ * R_ * D_, (long)C_ * R_ * D_, 1.f);
  softmax_k<<<(H_ * C_) / 4, 256, 0, stream>>>(awb, apb);
  gemm_bt<EP_CTX><<<dim3((R_ * D_) / 128, C_ / 128, H_), 256, 0, stream>>>(
      apb, vT, nullptr, ctxb, C_, R_ * D_, C_, (long)C_ * C_, (long)R_ * D_ * C_, 1.f);
  gemm_bt<EP_F32B><<<gProj, 256, 0, stream>>>(ctxb, rwoT, r_bo, x1, NT_, E_, E_, 0, 0, 1.f);

  // ---- stage 2: column attention ----
  ln_k<<<NT_ / 4, 256, 0, stream>>>(x1, ln2_s, ln2_b, hb);
  gemm_bt<EP_PERMQK><<<gProj, 256, 0, stream>>>(hb, cwqT, c_bq, qT, NT_, E_, E_, 0, 0, 0.125f); // D^-.5
  gemm_bt<EP_PERMQK><<<gProj, 256, 0, stream>>>(hb, cwkT, c_bk, kT, NT_, E_, E_, 0, 0, 1.f);
  gemm_bt<EP_VCOL ><<<gProj, 256, 0, stream>>>(hb, cwvT, c_bv, vT, NT_, E_, E_, 0, 0, 1.f);
  colattn<<<H_ * C_, 64, 0, stream>>>(qT, kT, vT, ctxb);
  gemm_bt<EP_F32B><<<gProj, 256, 0, stream>>>(ctxb, cwoT, c_bo, x1, NT_, E_, E_, 0, 0, 1.f);

  // ---- stage 3: FFN ----
  ln_k<<<NT_ / 4, 256, 0, stream>>>(x1, ln3_s, ln3_b, hb);
  gemm_bt<EP_GELU><<<dim3(F_ / 128, NT_ / 128, 1), 256, 0, stream>>>(hb, w1T, f_b1, g, NT_, F_, E_, 0, 0, 1.f);
  gemm_bt<EP_F32B><<<gProj, 256, 0, stream>>>(g, w2T, f_b2, d_out, NT_, E_, F_, 0, 0, 1.f);
}

// Round 3
// 753.241 us; speedup vs baseline: 1.1272x; 1.1272x over previous
//
#include <hip/hip_runtime.h>
#include <hip/hip_bf16.h>
#include <stdint.h>
#include <stddef.h>

#define R_ 64
#define C_ 256
#define E_ 768
#define H_ 12
#define F_ 3072
#define D_ 64
#define NT_ (R_*C_)   // 16384 tokens
#define HCRD_ ((size_t)H_*C_*R_*D_)

typedef float f32x4 __attribute__((ext_vector_type(4)));
typedef __bf16 bf16x8 __attribute__((ext_vector_type(8)));
typedef unsigned short us4 __attribute__((ext_vector_type(4)));

typedef __attribute__((address_space(3))) uint32_t lds_u32;
typedef __attribute__((address_space(1))) uint32_t glb_u32;

__device__ __forceinline__ void gld16(const uint16_t* g, uint16_t* l) {
  // async global->LDS, 16B per lane; LDS dest must be wave-uniform base + lane*16
  __builtin_amdgcn_global_load_lds((const glb_u32*)g, (lds_u32*)l, 16, 0, 0);
}

__device__ __forceinline__ uint16_t f2b(float f) { // fp32 -> bf16, native cvt (RNE)
  __bf16 h = (__bf16)f;
  return *(uint16_t*)&h;
}

// ---------------------------------------------------------------- GEMM
// C(MxN) = A(MxK bf16 rm, row stride lda) * B^T (B NxK bf16 rm, row stride ldb) + epilogue.
// 128x128 tile, BK=32, 256 threads (4 waves, 64x64 each via 4x4 frags of 16x16x32).
// 2-phase double-buffered LDS (T3-minimum): STAGE(t+1) issued before compute(t).
enum { EP_F32B = 0, EP_GELU = 1, EP_AW = 2, EP_CTX = 3, EP_QKVROW = 4, EP_QKVCOL = 5 };

template<int EP>
__global__ __launch_bounds__(256)
void gemm_bt(const uint16_t* __restrict__ A, const uint16_t* __restrict__ B,
             const float* __restrict__ bias, const float* __restrict__ biasK,
             const float* __restrict__ biasV, void* __restrict__ out,
             int M, int N, int K, int lda, int ldb, long sAz, long sBz, float scale)
{
  __shared__ uint16_t As[2][128 * 32];
  __shared__ uint16_t Bs[2][128 * 32];
  const int tid  = threadIdx.x;
  const int wave = tid >> 6, lane = tid & 63;
  const int z = blockIdx.z;
  const long bm = (long)blockIdx.y * 128;
  int kc = 0; long bnb = blockIdx.x;
  if constexpr (EP == EP_AW) { kc = blockIdx.x & 3; bnb = blockIdx.x >> 2; }
  const long bn = bnb * 128;
  const uint16_t* Ab = A + (long)z * sAz + bm * (long)lda + (long)kc * 1024;
  const uint16_t* Bb = B + (long)z * sBz + bn * (long)ldb + (long)kc * 1024;
  const int wr = (wave >> 1) * 64;
  const int wc = (wave & 1) * 64;
  const int lr = lane & 15;
  const int lq = lane >> 4;

  // staging map: slot t in [0,512): row = t>>2, k-offset = (t&3)*8  (16B per slot)
  const int t0 = tid, t1 = tid + 256;
  const int ar0 = t0 >> 2, ac0 = (t0 & 3) * 8;
  const int ar1 = t1 >> 2, ac1 = (t1 & 3) * 8;

  auto STAGE = [&](int bi, int kt) {
    gld16(Ab + (long)ar0 * lda + kt + ac0, &As[bi][t0 * 8]);
    gld16(Ab + (long)ar1 * lda + kt + ac1, &As[bi][t1 * 8]);
    gld16(Bb + (long)ar0 * ldb + kt + ac0, &Bs[bi][t0 * 8]);
    gld16(Bb + (long)ar1 * ldb + kt + ac1, &Bs[bi][t1 * 8]);
  };

  f32x4 acc[4][4];
#pragma unroll
  for (int i = 0; i < 4; ++i)
#pragma unroll
    for (int j = 0; j < 4; ++j) acc[i][j] = (f32x4){0.f, 0.f, 0.f, 0.f};

  const int nt = K >> 5;
  STAGE(0, 0);
  __syncthreads();                 // drains vmcnt before first compute
  int cur = 0;
  for (int t = 0; t < nt; ++t) {
    if (t + 1 < nt) STAGE(cur ^ 1, (t + 1) << 5);   // issue next tile first (overlap)

    bf16x8 af[4], bfm[4];
#pragma unroll
    for (int i = 0; i < 4; ++i) {
      af[i]  = *(const bf16x8*)&As[cur][(wr + i * 16 + lr) * 32 + lq * 8];
      bfm[i] = *(const bf16x8*)&Bs[cur][(wc + i * 16 + lr) * 32 + lq * 8];
    }
#pragma unroll
    for (int mi = 0; mi < 4; ++mi)
#pragma unroll
      for (int ni = 0; ni < 4; ++ni)
        acc[mi][ni] = __builtin_amdgcn_mfma_f32_16x16x32_bf16(af[mi], bfm[ni], acc[mi][ni], 0, 0, 0);

    __syncthreads();               // drain next-tile loads + barrier
    cur ^= 1;
  }

  // epilogue: C/D layout col = lane&15, row = (lane>>4)*4 + reg
#pragma unroll
  for (int mi = 0; mi < 4; ++mi) {
#pragma unroll
    for (int ni = 0; ni < 4; ++ni) {
#pragma unroll
      for (int r = 0; r < 4; ++r) {
        const long row = bm + wr + mi * 16 + lq * 4 + r;
        const long col = bn + wc + ni * 16 + lr;
        const float v = acc[mi][ni][r];
        if constexpr (EP == EP_F32B) {
          ((float*)out)[row * N + col] = v + bias[col];
        } else if constexpr (EP == EP_GELU) {
          const float t = v + bias[col];
          const float u = 0.7978845608028654f * (t + 0.044715f * t * t * t);
          const float e = __expf(2.f * u);
          const float th = 1.f - 2.f / (e + 1.f);   // tanh(u), inf-safe
          ((uint16_t*)out)[row * N + col] = f2b(0.5f * t * (1.f + th));
        } else if constexpr (EP == EP_AW) {
          ((float*)out)[((long)(z * 4 + kc) * M + row) * N + col] = v;
        } else if constexpr (EP == EP_CTX) {
          // out[(r)*C + i][E] at head z: col=(r,d), row=i
          ((uint16_t*)out)[((col >> 6) * C_ + row) * E_ + (long)z * 64 + (col & 63)] = f2b(v);
        } else {  // EP_QKVROW / EP_QKVCOL: fused QKV, col in [0,2304)
          const int grp = col >= 1536 ? 2 : (col >= 768 ? 1 : 0);   // wave-uniform per ni
          const long cc = col - (long)grp * 768;
          float val = v + (grp == 0 ? bias : grp == 1 ? biasK : biasV)[cc];
          if (grp == 0) val *= scale;
          const long h = cc >> 6, d = cc & 63, mlo = row & 255, mhi = row >> 8;
          uint16_t* o16 = (uint16_t*)out;
          if (grp < 2) {           // q,k -> (H,C,R,D)
            o16[(size_t)grp * HCRD_ + ((h * C_ + mlo) * R_ + mhi) * D_ + d] = f2b(val);
          } else if constexpr (EP == EP_QKVROW) {   // v -> (H, R*D, C)
            o16[2 * HCRD_ + ((h * R_ + mhi) * D_ + d) * C_ + mlo] = f2b(val);
          } else {                                  // v -> (H, C, D, R)
            o16[2 * HCRD_ + ((h * C_ + mlo) * D_ + d) * R_ + mhi] = f2b(val);
          }
        }
      }
    }
  }
}

// ---------------------------------------------------------------- LayerNorm (fp32 in -> bf16 out)
__global__ __launch_bounds__(256)
void ln_k(const float* __restrict__ x, const float* __restrict__ s, const float* __restrict__ b,
          uint16_t* __restrict__ out)
{
  const int wave = threadIdx.x >> 6, lane = threadIdx.x & 63;
  const long row = (long)blockIdx.x * 4 + wave;
  const float* xr = x + row * E_;
  f32x4 v[3];
  float sum = 0.f, sq = 0.f;
#pragma unroll
  for (int i = 0; i < 3; ++i) {
    v[i] = *(const f32x4*)(xr + (i * 64 + lane) * 4);
#pragma unroll
    for (int j = 0; j < 4; ++j) { sum += v[i][j]; sq += v[i][j] * v[i][j]; }
  }
#pragma unroll
  for (int m = 1; m < 64; m <<= 1) { sum += __shfl_xor(sum, m); sq += __shfl_xor(sq, m); }
  const float mu = sum * (1.f / E_);
  const float var = sq * (1.f / E_) - mu * mu;
  const float rs = rsqrtf(var + 1e-6f);
  uint16_t* orow = out + row * E_;
#pragma unroll
  for (int i = 0; i < 3; ++i) {
    const int e0 = (i * 64 + lane) * 4;
    us4 o;
#pragma unroll
    for (int j = 0; j < 4; ++j) o[j] = f2b((v[i][j] - mu) * rs * s[e0 + j] + b[e0 + j]);
    *(us4*)(orow + e0) = o;
  }
}

// ------------------------------------------------ softmax over 256, summing 4 split-K partials
__global__ __launch_bounds__(256)
void softmax_k4(const float* __restrict__ aw4, uint16_t* __restrict__ ap)
{
  const int wave = threadIdx.x >> 6, lane = threadIdx.x & 63;
  const long row = (long)blockIdx.x * 4 + wave;      // 0..H*C-1
  const long h = row >> 8, i = row & 255;
  f32x4 v = (f32x4){0.f, 0.f, 0.f, 0.f};
#pragma unroll
  for (int kc = 0; kc < 4; ++kc) {
    f32x4 t = *(const f32x4*)(aw4 + (((h * 4 + kc) * C_ + i) * C_) + lane * 4);
#pragma unroll
    for (int j = 0; j < 4; ++j) v[j] += t[j];
  }
  float m = fmaxf(fmaxf(v[0], v[1]), fmaxf(v[2], v[3]));
#pragma unroll
  for (int k = 1; k < 64; k <<= 1) m = fmaxf(m, __shfl_xor(m, k));
  f32x4 e; float s = 0.f;
#pragma unroll
  for (int j = 0; j < 4; ++j) { e[j] = __expf(v[j] - m); s += e[j]; }
#pragma unroll
  for (int k = 1; k < 64; k <<= 1) s += __shfl_xor(s, k);
  const float inv = 1.f / s;
  us4 o;
#pragma unroll
  for (int j = 0; j < 4; ++j) o[j] = f2b(e[j] * inv);
  *(us4*)(ap + row * C_ + lane * 4) = o;
}

// ---------------------------------------------------------------- weight transpose + fp32->bf16
// in: (K,N) fp32 row-major; out: (N,K) bf16 row-major
__global__ __launch_bounds__(256)
void tcvt(const float* __restrict__ in, uint16_t* __restrict__ out, int K, int N)
{
  __shared__ float t[32][33];
  const int tx = threadIdx.x, ty = threadIdx.y;   // block (32,8)
  const long k0 = (long)blockIdx.y * 32, n0 = (long)blockIdx.x * 32;
  for (int i = ty; i < 32; i += 8) t[i][tx] = in[(k0 + i) * N + n0 + tx];
  __syncthreads();
  for (int i = ty; i < 32; i += 8) out[(n0 + i) * K + k0 + tx] = f2b(t[tx][i]);
}

// ---------------------------------------------------------------- fused column attention
// one wave per (h,c): S=Q K^T (64x64), row softmax, ctx = P V. q,k: (H,C,R,D); v: (H,C,D,R)
__global__ __launch_bounds__(64)
void colattn(const uint16_t* __restrict__ q, const uint16_t* __restrict__ k,
             const uint16_t* __restrict__ v, uint16_t* __restrict__ ctx)
{
  __shared__ uint16_t Qs[64 * 64];   // reused for P after S is consumed
  __shared__ uint16_t Ks[64 * 64];
  __shared__ uint16_t Vs[64 * 64];
  const int hc = blockIdx.x;
  const int h = hc >> 8, c = hc & 255;
  const int lane = threadIdx.x;
  const uint16_t* qb = q + (long)hc * (R_ * D_);
  const uint16_t* kb = k + (long)hc * (R_ * D_);
  const uint16_t* vb = v + (long)hc * (D_ * R_);
#pragma unroll
  for (int it = 0; it < 8; ++it) {
    const int o = (it * 64 + lane) * 8;
    gld16(qb + o, &Qs[o]);
    gld16(kb + o, &Ks[o]);
    gld16(vb + o, &Vs[o]);
  }
  asm volatile("s_waitcnt vmcnt(0)" ::: "memory");
  __builtin_amdgcn_sched_barrier(0);

  const int lr = lane & 15, lq = lane >> 4;
  f32x4 acc[4][4];
#pragma unroll
  for (int i = 0; i < 4; ++i)
#pragma unroll
    for (int j = 0; j < 4; ++j) acc[i][j] = (f32x4){0.f, 0.f, 0.f, 0.f};

#pragma unroll
  for (int kt = 0; kt < 2; ++kt) {
    bf16x8 af[4], bfm[4];
#pragma unroll
    for (int i = 0; i < 4; ++i) {
      af[i]  = *(const bf16x8*)&Qs[(i * 16 + lr) * 64 + kt * 32 + lq * 8];
      bfm[i] = *(const bf16x8*)&Ks[(i * 16 + lr) * 64 + kt * 32 + lq * 8];
    }
#pragma unroll
    for (int mi = 0; mi < 4; ++mi)
#pragma unroll
      for (int ni = 0; ni < 4; ++ni)
        acc[mi][ni] = __builtin_amdgcn_mfma_f32_16x16x32_bf16(af[mi], bfm[ni], acc[mi][ni], 0, 0, 0);
  }

  // row softmax: row i = mi*16+lq*4+r spans cols ni*16+lr across the 16-lane group
#pragma unroll
  for (int mi = 0; mi < 4; ++mi) {
#pragma unroll
    for (int r = 0; r < 4; ++r) {
      float mx = fmaxf(fmaxf(acc[mi][0][r], acc[mi][1][r]), fmaxf(acc[mi][2][r], acc[mi][3][r]));
#pragma unroll
      for (int s = 1; s < 16; s <<= 1) mx = fmaxf(mx, __shfl_xor(mx, s));
      float e0 = __expf(acc[mi][0][r] - mx), e1 = __expf(acc[mi][1][r] - mx);
      float e2 = __expf(acc[mi][2][r] - mx), e3 = __expf(acc[mi][3][r] - mx);
      float sum = e0 + e1 + e2 + e3;
#pragma unroll
      for (int s = 1; s < 16; s <<= 1) sum += __shfl_xor(sum, s);
      const float inv = 1.f / sum;
      const int i = mi * 16 + lq * 4 + r;
      Qs[i * 64 +  0 + lr] = f2b(e0 * inv);
      Qs[i * 64 + 16 + lr] = f2b(e1 * inv);
      Qs[i * 64 + 32 + lr] = f2b(e2 * inv);
      Qs[i * 64 + 48 + lr] = f2b(e3 * inv);
    }
  }
  __syncthreads();

  f32x4 o_[4][4];
#pragma unroll
  for (int i = 0; i < 4; ++i)
#pragma unroll
    for (int j = 0; j < 4; ++j) o_[i][j] = (f32x4){0.f, 0.f, 0.f, 0.f};

#pragma unroll
  for (int kt = 0; kt < 2; ++kt) {
    bf16x8 pa[4], vv[4];
#pragma unroll
    for (int i = 0; i < 4; ++i) {
      pa[i] = *(const bf16x8*)&Qs[(i * 16 + lr) * 64 + kt * 32 + lq * 8];
      vv[i] = *(const bf16x8*)&Vs[(i * 16 + lr) * 64 + kt * 32 + lq * 8];
    }
#pragma unroll
    for (int mi = 0; mi < 4; ++mi)
#pragma unroll
      for (int ni = 0; ni < 4; ++ni)
        o_[mi][ni] = __builtin_amdgcn_mfma_f32_16x16x32_bf16(pa[mi], vv[ni], o_[mi][ni], 0, 0, 0);
  }

#pragma unroll
  for (int mi = 0; mi < 4; ++mi)
#pragma unroll
    for (int ni = 0; ni < 4; ++ni)
#pragma unroll
      for (int r = 0; r < 4; ++r) {
        const int i = mi * 16 + lq * 4 + r;
        const int d = ni * 16 + lr;
        ctx[((long)i * C_ + c) * E_ + h * 64 + d] = f2b(o_[mi][ni][r]);
      }
}

// ---------------------------------------------------------------- host launch
extern "C" void kernel_launch(void* const* d_in, const int* in_sizes, int n_in,
                              void* d_out, int out_size, void* d_ws, size_t ws_size,
                              hipStream_t stream)
{
  (void)in_sizes; (void)n_in; (void)out_size; (void)ws_size;
  const float* x     = (const float*)d_in[0];
  const float* ln1_s = (const float*)d_in[1];
  const float* ln1_b = (const float*)d_in[2];
  const float* r_wq  = (const float*)d_in[3];
  const float* r_bq  = (const float*)d_in[4];
  const float* r_wk  = (const float*)d_in[5];
  const float* r_bk  = (const float*)d_in[6];
  const float* r_wv  = (const float*)d_in[7];
  const float* r_bv  = (const float*)d_in[8];
  const float* r_wo  = (const float*)d_in[9];
  const float* r_bo  = (const float*)d_in[10];
  const float* ln2_s = (const float*)d_in[11];
  const float* ln2_b = (const float*)d_in[12];
  const float* c_wq  = (const float*)d_in[13];
  const float* c_bq  = (const float*)d_in[14];
  const float* c_wk  = (const float*)d_in[15];
  const float* c_bk  = (const float*)d_in[16];
  const float* c_wv  = (const float*)d_in[17];
  const float* c_bv  = (const float*)d_in[18];
  const float* c_wo  = (const float*)d_in[19];
  const float* c_bo  = (const float*)d_in[20];
  const float* ln3_s = (const float*)d_in[21];
  const float* ln3_b = (const float*)d_in[22];
  const float* f_w1  = (const float*)d_in[23];
  const float* f_b1  = (const float*)d_in[24];
  const float* f_w2  = (const float*)d_in[25];
  const float* f_b2  = (const float*)d_in[26];

  // ---------- workspace layout (≈139.5 MiB peak; aliasing commented) ----------
  uint8_t* p = (uint8_t*)d_ws;
  auto take = [&p](size_t n) { uint8_t* r = p; p += (n + 255) & ~(size_t)255; return r; };

  uint16_t* wqkv1 = (uint16_t*)take((size_t)3 * E_ * E_ * 2);   // fused QKV wT, stage 1
  uint16_t* wqkv2 = (uint16_t*)take((size_t)3 * E_ * E_ * 2);   // fused QKV wT, stage 2
  uint16_t* rwoT  = (uint16_t*)take((size_t)E_ * E_ * 2);
  uint16_t* cwoT  = (uint16_t*)take((size_t)E_ * E_ * 2);
  uint16_t* w1T   = (uint16_t*)take((size_t)E_ * F_ * 2);       // (F,E)
  uint16_t* w2T   = (uint16_t*)take((size_t)F_ * E_ * 2);       // (E,F)
  uint16_t* hb    = (uint16_t*)take((size_t)NT_ * E_ * 2);
  // qkv slab: 3 x 25.166 MB contiguous (QKV epilogue indexes off qkvT);
  // g (NT*F bf16, stage 3) aliases it.
  uint16_t* qkvT  = (uint16_t*)take(3 * HCRD_ * 2);
  uint16_t* qT = qkvT, *kT = qkvT + HCRD_, *vT = qkvT + 2 * HCRD_;
  uint16_t* ctxb  = (uint16_t*)take((size_t)NT_ * E_ * 2);
  uint16_t* apb   = (uint16_t*)take((size_t)H_ * C_ * C_ * 2);
  uint16_t* g     = qkvT;          // alias: stage-3 FFN hidden over dead q/k/v
  float*    awb4  = (float*)ctxb;  // alias: 4 split-K partials (12.6 MB) dead before ctxb written
  float*    x1    = (float*)d_out; // alias: inter-stage fp32 activation in output buf

  const dim3 tb32(32, 8);
  const dim3 gEE(E_ / 32, E_ / 32);
  tcvt<<<gEE, tb32, 0, stream>>>(r_wq, wqkv1 + 0 * E_ * E_, E_, E_);
  tcvt<<<gEE, tb32, 0, stream>>>(r_wk, wqkv1 + 1 * E_ * E_, E_, E_);
  tcvt<<<gEE, tb32, 0, stream>>>(r_wv, wqkv1 + 2 * E_ * E_, E_, E_);
  tcvt<<<gEE, tb32, 0, stream>>>(c_wq, wqkv2 + 0 * E_ * E_, E_, E_);
  tcvt<<<gEE, tb32, 0, stream>>>(c_wk, wqkv2 + 1 * E_ * E_, E_, E_);
  tcvt<<<gEE, tb32, 0, stream>>>(c_wv, wqkv2 + 2 * E_ * E_, E_, E_);
  tcvt<<<gEE, tb32, 0, stream>>>(r_wo, rwoT, E_, E_);
  tcvt<<<gEE, tb32, 0, stream>>>(c_wo, cwoT, E_, E_);
  tcvt<<<dim3(F_ / 32, E_ / 32), tb32, 0, stream>>>(f_w1, w1T, E_, F_);  // -> (F,E)
  tcvt<<<dim3(E_ / 32, F_ / 32), tb32, 0, stream>>>(f_w2, w2T, F_, E_);  // -> (E,F)

  const dim3 gProj(E_ / 128, NT_ / 128, 1);
  const dim3 gQKV((3 * E_) / 128, NT_ / 128, 1);

  // ---- stage 1: tied-row attention ----
  ln_k<<<NT_ / 4, 256, 0, stream>>>(x, ln1_s, ln1_b, hb);
  gemm_bt<EP_QKVROW><<<gQKV, 256, 0, stream>>>(hb, wqkv1, r_bq, r_bk, r_bv, qkvT,
      NT_, 3 * E_, E_, E_, E_, 0, 0, 0.015625f);   // q-scale: D^-.5/sqrt(R)
  gemm_bt<EP_AW><<<dim3(8, C_ / 128, H_), 256, 0, stream>>>(qT, kT, nullptr, nullptr, nullptr, awb4,
      C_, C_, 1024, R_ * D_, R_ * D_, (long)C_ * R_ * D_, (long)C_ * R_ * D_, 1.f);  // split-K=4
  softmax_k4<<<(H_ * C_) / 4, 256, 0, stream>>>(awb4, apb);
  gemm_bt<EP_CTX><<<dim3((R_ * D_) / 128, C_ / 128, H_), 256, 0, stream>>>(apb, vT, nullptr, nullptr, nullptr,
      ctxb, C_, R_ * D_, C_, C_, C_, (long)C_ * C_, (long)R_ * D_ * C_, 1.f);
  gemm_bt<EP_F32B><<<gProj, 256, 0, stream>>>(ctxb, rwoT, r_bo, nullptr, nullptr, x1,
      NT_, E_, E_, E_, E_, 0, 0, 1.f);

  // ---- stage 2: column attention ----
  ln_k<<<NT_ / 4, 256, 0, stream>>>(x1, ln2_s, ln2_b, hb);
  gemm_bt<EP_QKVCOL><<<gQKV, 256, 0, stream>>>(hb, wqkv2, c_bq, c_bk, c_bv, qkvT,
      NT_, 3 * E_, E_, E_, E_, 0, 0, 0.125f);      // q-scale: D^-.5
  colattn<<<H_ * C_, 64, 0, stream>>>(qT, kT, vT, ctxb);
  gemm_bt<EP_F32B><<<gProj, 256, 0, stream>>>(ctxb, cwoT, c_bo, nullptr, nullptr, x1,
      NT_, E_, E_, E_, E_, 0, 0, 1.f);

  // ---- stage 3: FFN ----
  ln_k<<<NT_ / 4, 256, 0, stream>>>(x1, ln3_s, ln3_b, hb);
  gemm_bt<EP_GELU><<<dim3(F_ / 128, NT_ / 128, 1), 256, 0, stream>>>(hb, w1T, f_b1, nullptr, nullptr, g,
      NT_, F_, E_, E_, E_, 0, 0, 1.f);
  gemm_bt<EP_F32B><<<gProj, 256, 0, stream>>>(g, w2T, f_b2, nullptr, nullptr, d_out,
      NT_, E_, F_, F_, F_, 0, 0, 1.f);
}

// Round 4
// 598.382 us; speedup vs baseline: 1.4190x; 1.2588x over previous
//
#include <hip/hip_runtime.h>
#include <hip/hip_bf16.h>
#include <stdint.h>
#include <stddef.h>

#define R_ 64
#define C_ 256
#define E_ 768
#define H_ 12
#define F_ 3072
#define D_ 64
#define NT_ (R_*C_)   // 16384 tokens
#define HCRD_ ((size_t)H_*C_*R_*D_)

typedef float f32x4 __attribute__((ext_vector_type(4)));
typedef __bf16 bf16x8 __attribute__((ext_vector_type(8)));
typedef unsigned short us4 __attribute__((ext_vector_type(4)));
typedef unsigned short us8 __attribute__((ext_vector_type(8)));

typedef __attribute__((address_space(3))) uint32_t lds_u32;
typedef __attribute__((address_space(1))) uint32_t glb_u32;

__device__ __forceinline__ void gld16(const uint16_t* g, uint16_t* l) {
  // async global->LDS, 16B per lane; LDS dest must be wave-uniform base + lane*16
  __builtin_amdgcn_global_load_lds((const glb_u32*)g, (lds_u32*)l, 16, 0, 0);
}

__device__ __forceinline__ uint16_t f2b(float f) { // fp32 -> bf16, native cvt (RNE)
  __bf16 h = (__bf16)f;
  return *(uint16_t*)&h;
}

// ---------------------------------------------------------------- GEMM
// C(MxN) = A(MxK bf16 rm, row stride lda) * B^T (B NxK bf16 rm, row stride ldb) + epilogue.
// 128x128 tile, BK=32, 256 threads (4 waves, 64x64 each via 4x4 frags of 16x16x32).
// 2-phase double-buffered LDS; optional XCD-chunked block swizzle (SWZ, needs nwg%8==0);
// optional A-row permutation m -> token (m&63)*256 + (m>>6) (PERM, stage-2 QKV).
enum { EP_F32B = 0, EP_GELU = 1, EP_AW = 2, EP_CTX = 3, EP_QKVROW = 4, EP_QKVCOL = 5 };

template<int EP, bool SWZ, bool PERM>
__global__ __launch_bounds__(256)
void gemm_bt(const uint16_t* __restrict__ A, const uint16_t* __restrict__ B,
             const float* __restrict__ bias, const float* __restrict__ biasK,
             const float* __restrict__ biasV, void* __restrict__ out,
             int M, int N, int K, int lda, int ldb, long sAz, long sBz, float scale)
{
  __shared__ uint16_t As[2][128 * 32];
  __shared__ uint16_t Bs[2][128 * 32];
  const int tid  = threadIdx.x;
  const int wave = tid >> 6, lane = tid & 63;
  const int z = blockIdx.z;

  int bx = blockIdx.x, by = blockIdx.y;
  if constexpr (SWZ) {   // XCD-chunked bijective swizzle (dispatch d -> XCD d%8)
    int lin = blockIdx.x + gridDim.x * blockIdx.y;
    const int q = (gridDim.x * gridDim.y) >> 3;
    const int wid = (lin & 7) * q + (lin >> 3);
    bx = wid % gridDim.x; by = wid / gridDim.x;
  }

  const long bm = (long)by * 128;
  int kc = 0; long bnb = bx;
  if constexpr (EP == EP_AW) { kc = bx & 3; bnb = bx >> 2; }
  const long bn = bnb * 128;
  const uint16_t* Bb = B + (long)z * sBz + bn * (long)ldb + (long)kc * 1024;
  const int wr = (wave >> 1) * 64;
  const int wc = (wave & 1) * 64;
  const int lr = lane & 15;
  const int lq = lane >> 4;

  // staging map: slot t in [0,512): row = t>>2, k-offset = (t&3)*8  (16B per slot)
  const int t0 = tid, t1 = tid + 256;
  const int ar0 = t0 >> 2, ac0 = (t0 & 3) * 8;
  const int ar1 = t1 >> 2, ac1 = (t1 & 3) * 8;

  long am0 = bm + ar0, am1 = bm + ar1;
  if constexpr (PERM) {   // logical row m reads token (m&63)*256 + (m>>6)
    am0 = ((am0 & 63) << 8) | (am0 >> 6);
    am1 = ((am1 & 63) << 8) | (am1 >> 6);
  }
  const uint16_t* a0p = A + (long)z * sAz + am0 * (long)lda + (long)kc * 1024;
  const uint16_t* a1p = A + (long)z * sAz + am1 * (long)lda + (long)kc * 1024;
  const uint16_t* b0p = Bb + (long)ar0 * ldb;
  const uint16_t* b1p = Bb + (long)ar1 * ldb;

  auto STAGE = [&](int bi, int kt) {
    gld16(a0p + kt + ac0, &As[bi][t0 * 8]);
    gld16(a1p + kt + ac1, &As[bi][t1 * 8]);
    gld16(b0p + kt + ac0, &Bs[bi][t0 * 8]);
    gld16(b1p + kt + ac1, &Bs[bi][t1 * 8]);
  };

  f32x4 acc[4][4];
#pragma unroll
  for (int i = 0; i < 4; ++i)
#pragma unroll
    for (int j = 0; j < 4; ++j) acc[i][j] = (f32x4){0.f, 0.f, 0.f, 0.f};

  const int nt = K >> 5;
  STAGE(0, 0);
  __syncthreads();                 // drains vmcnt before first compute
  int cur = 0;
  for (int t = 0; t < nt; ++t) {
    if (t + 1 < nt) STAGE(cur ^ 1, (t + 1) << 5);   // issue next tile first (overlap)

    bf16x8 af[4], bfm[4];
#pragma unroll
    for (int i = 0; i < 4; ++i) {
      af[i]  = *(const bf16x8*)&As[cur][(wr + i * 16 + lr) * 32 + lq * 8];
      bfm[i] = *(const bf16x8*)&Bs[cur][(wc + i * 16 + lr) * 32 + lq * 8];
    }
#pragma unroll
    for (int mi = 0; mi < 4; ++mi)
#pragma unroll
      for (int ni = 0; ni < 4; ++ni)
        acc[mi][ni] = __builtin_amdgcn_mfma_f32_16x16x32_bf16(af[mi], bfm[ni], acc[mi][ni], 0, 0, 0);

    __syncthreads();               // drain next-tile loads + barrier
    cur ^= 1;
  }

  // ------------------------------------------------------------- epilogue
  if constexpr (EP == EP_F32B) {
#pragma unroll
    for (int mi = 0; mi < 4; ++mi)
#pragma unroll
      for (int ni = 0; ni < 4; ++ni)
#pragma unroll
        for (int r = 0; r < 4; ++r) {
          const long row = bm + wr + mi * 16 + lq * 4 + r;
          const long col = bn + wc + ni * 16 + lr;
          ((float*)out)[row * N + col] = acc[mi][ni][r] + bias[col];
        }
  } else if constexpr (EP == EP_AW) {
#pragma unroll
    for (int mi = 0; mi < 4; ++mi)
#pragma unroll
      for (int ni = 0; ni < 4; ++ni)
#pragma unroll
        for (int r = 0; r < 4; ++r) {
          const long row = bm + wr + mi * 16 + lq * 4 + r;
          const long col = bn + wc + ni * 16 + lr;
          ((float*)out)[((long)(z * 4 + kc) * M + row) * N + col] = acc[mi][ni][r];
        }
  } else if constexpr (EP == EP_CTX) {
#pragma unroll
    for (int mi = 0; mi < 4; ++mi)
#pragma unroll
      for (int ni = 0; ni < 4; ++ni)
#pragma unroll
        for (int r = 0; r < 4; ++r) {
          const long row = bm + wr + mi * 16 + lq * 4 + r;
          const long col = bn + wc + ni * 16 + lr;
          ((uint16_t*)out)[((col >> 6) * C_ + row) * E_ + (long)z * 64 + (col & 63)] =
              f2b(acc[mi][ni][r]);
        }
  } else {
    // slab-based coalesced epilogue (QKVROW / QKVCOL / GELU).
    // Reuse As/Bs (dead after final barrier) as 4 wave-private 8 KB slabs.
    // XOR-swizzle keyed on slab row keeps both dump and readout conflict-light.
    uint16_t* slab = (wave < 2) ? &As[wave][0] : &Bs[wave - 2][0];
    const long colb = bn + wc;                 // wave tile col base (64-wide)
    int grp = 0; long cc0 = colb;
    const float* bb = bias;
    if constexpr (EP != EP_GELU) {
      grp = colb >= 1536 ? 2 : (colb >= 768 ? 1 : 0);
      cc0 = colb - (long)grp * 768;
      bb = grp == 0 ? bias : (grp == 1 ? biasK : biasV);
    }
    const bool tr = (EP != EP_GELU) && (grp == 2);   // V dumps transposed [d][tok]

    // dump 64x64 tile into slab (bf16)
#pragma unroll
    for (int mi = 0; mi < 4; ++mi)
#pragma unroll
      for (int ni = 0; ni < 4; ++ni)
#pragma unroll
        for (int r = 0; r < 4; ++r) {
          const int lrow = mi * 16 + lq * 4 + r;
          const int lcol = ni * 16 + lr;
          float val;
          if constexpr (EP == EP_GELU) {
            const float t = acc[mi][ni][r] + bias[colb + lcol];
            const float u = 0.7978845608028654f * (t + 0.044715f * t * t * t);
            const float e = __expf(2.f * u);
            val = 0.5f * t * (2.f - 2.f / (e + 1.f));   // t*(1+tanh(u)) inf-safe
          } else {
            val = acc[mi][ni][r] + bb[cc0 + lcol];
            if (grp == 0) val *= scale;
          }
          const int sr = tr ? lcol : lrow;
          const int sc = tr ? lrow : lcol;
          const int psc = (sc & 7) | ((((sc >> 3) ^ (sr & 7))) << 3);
          slab[sr * 64 + psc] = f2b(val);
        }

    // destination base / row stride (wave-uniform)
    uint16_t* o16 = (uint16_t*)out;
    long obase, rstride;
    if constexpr (EP == EP_GELU) {
      obase = (bm + wr) * (long)N + colb; rstride = N;
    } else {
      const long h = cc0 >> 6;
      const long m0 = bm + wr;
      if constexpr (EP == EP_QKVROW) {     // tile rows = tokens (fixed r, c varies)
        const long rr = m0 >> 8, c0 = m0 & 255;
        if (grp < 2) { obase = (size_t)grp * HCRD_ + ((h * C_ + c0) * R_ + rr) * D_; rstride = R_ * D_; }
        else         { obase = 2 * HCRD_ + ((h * R_ + rr) * D_) * C_ + c0;           rstride = C_; }
      } else {                             // QKVCOL: tile rows = r (fixed c)
        const long cq = m0 >> 6;
        if (grp < 2) { obase = (size_t)grp * HCRD_ + ((h * C_ + cq) * R_) * D_; rstride = D_; }
        else         { obase = 2 * HCRD_ + ((h * C_ + cq) * D_) * R_;           rstride = R_; }
      }
    }

    // readout: 8 passes, 16B per lane, fully coalesced
    const int rl = lane >> 3, chn = lane & 7;
#pragma unroll
    for (int pp = 0; pp < 8; ++pp) {
      const int srow = pp * 8 + rl;
      const int pch = chn ^ (srow & 7);
      us8 wv = *(const us8*)&slab[srow * 64 + pch * 8];
      *(us8*)(o16 + obase + (long)srow * rstride + chn * 8) = wv;
    }
  }
}

// ---------------------------------------------------------------- LayerNorm (fp32 in -> bf16 out)
__global__ __launch_bounds__(256)
void ln_k(const float* __restrict__ x, const float* __restrict__ s, const float* __restrict__ b,
          uint16_t* __restrict__ out)
{
  const int wave = threadIdx.x >> 6, lane = threadIdx.x & 63;
  const long row = (long)blockIdx.x * 4 + wave;
  const float* xr = x + row * E_;
  f32x4 v[3];
  float sum = 0.f, sq = 0.f;
#pragma unroll
  for (int i = 0; i < 3; ++i) {
    v[i] = *(const f32x4*)(xr + (i * 64 + lane) * 4);
#pragma unroll
    for (int j = 0; j < 4; ++j) { sum += v[i][j]; sq += v[i][j] * v[i][j]; }
  }
#pragma unroll
  for (int m = 1; m < 64; m <<= 1) { sum += __shfl_xor(sum, m); sq += __shfl_xor(sq, m); }
  const float mu = sum * (1.f / E_);
  const float var = sq * (1.f / E_) - mu * mu;
  const float rs = rsqrtf(var + 1e-6f);
  uint16_t* orow = out + row * E_;
#pragma unroll
  for (int i = 0; i < 3; ++i) {
    const int e0 = (i * 64 + lane) * 4;
    us4 o;
#pragma unroll
    for (int j = 0; j < 4; ++j) o[j] = f2b((v[i][j] - mu) * rs * s[e0 + j] + b[e0 + j]);
    *(us4*)(orow + e0) = o;
  }
}

// ------------------------------------------------ softmax over 256, summing 4 split-K partials
__global__ __launch_bounds__(256)
void softmax_k4(const float* __restrict__ aw4, uint16_t* __restrict__ ap)
{
  const int wave = threadIdx.x >> 6, lane = threadIdx.x & 63;
  const long row = (long)blockIdx.x * 4 + wave;      // 0..H*C-1
  const long h = row >> 8, i = row & 255;
  f32x4 v = (f32x4){0.f, 0.f, 0.f, 0.f};
#pragma unroll
  for (int kc = 0; kc < 4; ++kc) {
    f32x4 t = *(const f32x4*)(aw4 + (((h * 4 + kc) * C_ + i) * C_) + lane * 4);
#pragma unroll
    for (int j = 0; j < 4; ++j) v[j] += t[j];
  }
  float m = fmaxf(fmaxf(v[0], v[1]), fmaxf(v[2], v[3]));
#pragma unroll
  for (int k = 1; k < 64; k <<= 1) m = fmaxf(m, __shfl_xor(m, k));
  f32x4 e; float s = 0.f;
#pragma unroll
  for (int j = 0; j < 4; ++j) { e[j] = __expf(v[j] - m); s += e[j]; }
#pragma unroll
  for (int k = 1; k < 64; k <<= 1) s += __shfl_xor(s, k);
  const float inv = 1.f / s;
  us4 o;
#pragma unroll
  for (int j = 0; j < 4; ++j) o[j] = f2b(e[j] * inv);
  *(us4*)(ap + row * C_ + lane * 4) = o;
}

// ---------------------------------------------------------------- weight transpose + fp32->bf16
// in: (K,N) fp32 row-major; out: (N,K) bf16 row-major
__global__ __launch_bounds__(256)
void tcvt(const float* __restrict__ in, uint16_t* __restrict__ out, int K, int N)
{
  __shared__ float t[32][33];
  const int tx = threadIdx.x, ty = threadIdx.y;   // block (32,8)
  const long k0 = (long)blockIdx.y * 32, n0 = (long)blockIdx.x * 32;
  for (int i = ty; i < 32; i += 8) t[i][tx] = in[(k0 + i) * N + n0 + tx];
  __syncthreads();
  for (int i = ty; i < 32; i += 8) out[(n0 + i) * K + k0 + tx] = f2b(t[tx][i]);
}

// ---------------------------------------------------------------- fused column attention
// one wave per (h,c): S=Q K^T (64x64), row softmax, ctx = P V. q,k: (H,C,R,D); v: (H,C,D,R)
__global__ __launch_bounds__(64)
void colattn(const uint16_t* __restrict__ q, const uint16_t* __restrict__ k,
             const uint16_t* __restrict__ v, uint16_t* __restrict__ ctx)
{
  __shared__ uint16_t Qs[64 * 64];   // reused for P after S is consumed
  __shared__ uint16_t Ks[64 * 64];
  __shared__ uint16_t Vs[64 * 64];
  const int hc = blockIdx.x;
  const int h = hc >> 8, c = hc & 255;
  const int lane = threadIdx.x;
  const uint16_t* qb = q + (long)hc * (R_ * D_);
  const uint16_t* kb = k + (long)hc * (R_ * D_);
  const uint16_t* vb = v + (long)hc * (D_ * R_);
#pragma unroll
  for (int it = 0; it < 8; ++it) {
    const int o = (it * 64 + lane) * 8;
    gld16(qb + o, &Qs[o]);
    gld16(kb + o, &Ks[o]);
    gld16(vb + o, &Vs[o]);
  }
  asm volatile("s_waitcnt vmcnt(0)" ::: "memory");
  __builtin_amdgcn_sched_barrier(0);

  const int lr = lane & 15, lq = lane >> 4;
  f32x4 acc[4][4];
#pragma unroll
  for (int i = 0; i < 4; ++i)
#pragma unroll
    for (int j = 0; j < 4; ++j) acc[i][j] = (f32x4){0.f, 0.f, 0.f, 0.f};

#pragma unroll
  for (int kt = 0; kt < 2; ++kt) {
    bf16x8 af[4], bfm[4];
#pragma unroll
    for (int i = 0; i < 4; ++i) {
      af[i]  = *(const bf16x8*)&Qs[(i * 16 + lr) * 64 + kt * 32 + lq * 8];
      bfm[i] = *(const bf16x8*)&Ks[(i * 16 + lr) * 64 + kt * 32 + lq * 8];
    }
#pragma unroll
    for (int mi = 0; mi < 4; ++mi)
#pragma unroll
      for (int ni = 0; ni < 4; ++ni)
        acc[mi][ni] = __builtin_amdgcn_mfma_f32_16x16x32_bf16(af[mi], bfm[ni], acc[mi][ni], 0, 0, 0);
  }

  // row softmax: row i = mi*16+lq*4+r spans cols ni*16+lr across the 16-lane group
#pragma unroll
  for (int mi = 0; mi < 4; ++mi) {
#pragma unroll
    for (int r = 0; r < 4; ++r) {
      float mx = fmaxf(fmaxf(acc[mi][0][r], acc[mi][1][r]), fmaxf(acc[mi][2][r], acc[mi][3][r]));
#pragma unroll
      for (int s = 1; s < 16; s <<= 1) mx = fmaxf(mx, __shfl_xor(mx, s));
      float e0 = __expf(acc[mi][0][r] - mx), e1 = __expf(acc[mi][1][r] - mx);
      float e2 = __expf(acc[mi][2][r] - mx), e3 = __expf(acc[mi][3][r] - mx);
      float sum = e0 + e1 + e2 + e3;
#pragma unroll
      for (int s = 1; s < 16; s <<= 1) sum += __shfl_xor(sum, s);
      const float inv = 1.f / sum;
      const int i = mi * 16 + lq * 4 + r;
      Qs[i * 64 +  0 + lr] = f2b(e0 * inv);
      Qs[i * 64 + 16 + lr] = f2b(e1 * inv);
      Qs[i * 64 + 32 + lr] = f2b(e2 * inv);
      Qs[i * 64 + 48 + lr] = f2b(e3 * inv);
    }
  }
  __syncthreads();

  f32x4 o_[4][4];
#pragma unroll
  for (int i = 0; i < 4; ++i)
#pragma unroll
    for (int j = 0; j < 4; ++j) o_[i][j] = (f32x4){0.f, 0.f, 0.f, 0.f};

#pragma unroll
  for (int kt = 0; kt < 2; ++kt) {
    bf16x8 pa[4], vv[4];
#pragma unroll
    for (int i = 0; i < 4; ++i) {
      pa[i] = *(const bf16x8*)&Qs[(i * 16 + lr) * 64 + kt * 32 + lq * 8];
      vv[i] = *(const bf16x8*)&Vs[(i * 16 + lr) * 64 + kt * 32 + lq * 8];
    }
#pragma unroll
    for (int mi = 0; mi < 4; ++mi)
#pragma unroll
      for (int ni = 0; ni < 4; ++ni)
        o_[mi][ni] = __builtin_amdgcn_mfma_f32_16x16x32_bf16(pa[mi], vv[ni], o_[mi][ni], 0, 0, 0);
  }

#pragma unroll
  for (int mi = 0; mi < 4; ++mi)
#pragma unroll
    for (int ni = 0; ni < 4; ++ni)
#pragma unroll
      for (int r = 0; r < 4; ++r) {
        const int i = mi * 16 + lq * 4 + r;
        const int d = ni * 16 + lr;
        ctx[((long)i * C_ + c) * E_ + h * 64 + d] = f2b(o_[mi][ni][r]);
      }
}

// ---------------------------------------------------------------- host launch
extern "C" void kernel_launch(void* const* d_in, const int* in_sizes, int n_in,
                              void* d_out, int out_size, void* d_ws, size_t ws_size,
                              hipStream_t stream)
{
  (void)in_sizes; (void)n_in; (void)out_size; (void)ws_size;
  const float* x     = (const float*)d_in[0];
  const float* ln1_s = (const float*)d_in[1];
  const float* ln1_b = (const float*)d_in[2];
  const float* r_wq  = (const float*)d_in[3];
  const float* r_bq  = (const float*)d_in[4];
  const float* r_wk  = (const float*)d_in[5];
  const float* r_bk  = (const float*)d_in[6];
  const float* r_wv  = (const float*)d_in[7];
  const float* r_bv  = (const float*)d_in[8];
  const float* r_wo  = (const float*)d_in[9];
  const float* r_bo  = (const float*)d_in[10];
  const float* ln2_s = (const float*)d_in[11];
  const float* ln2_b = (const float*)d_in[12];
  const float* c_wq  = (const float*)d_in[13];
  const float* c_bq  = (const float*)d_in[14];
  const float* c_wk  = (const float*)d_in[15];
  const float* c_bk  = (const float*)d_in[16];
  const float* c_wv  = (const float*)d_in[17];
  const float* c_bv  = (const float*)d_in[18];
  const float* c_wo  = (const float*)d_in[19];
  const float* c_bo  = (const float*)d_in[20];
  const float* ln3_s = (const float*)d_in[21];
  const float* ln3_b = (const float*)d_in[22];
  const float* f_w1  = (const float*)d_in[23];
  const float* f_b1  = (const float*)d_in[24];
  const float* f_w2  = (const float*)d_in[25];
  const float* f_b2  = (const float*)d_in[26];

  // ---------- workspace layout (≈139.5 MiB peak; aliasing commented) ----------
  uint8_t* p = (uint8_t*)d_ws;
  auto take = [&p](size_t n) { uint8_t* r = p; p += (n + 255) & ~(size_t)255; return r; };

  uint16_t* wqkv1 = (uint16_t*)take((size_t)3 * E_ * E_ * 2);   // fused QKV wT, stage 1
  uint16_t* wqkv2 = (uint16_t*)take((size_t)3 * E_ * E_ * 2);   // fused QKV wT, stage 2
  uint16_t* rwoT  = (uint16_t*)take((size_t)E_ * E_ * 2);
  uint16_t* cwoT  = (uint16_t*)take((size_t)E_ * E_ * 2);
  uint16_t* w1T   = (uint16_t*)take((size_t)E_ * F_ * 2);       // (F,E)
  uint16_t* w2T   = (uint16_t*)take((size_t)F_ * E_ * 2);       // (E,F)
  uint16_t* hb    = (uint16_t*)take((size_t)NT_ * E_ * 2);
  // qkv slab: 3 x 25.166 MB contiguous; g (NT*F bf16, stage 3) aliases it.
  uint16_t* qkvT  = (uint16_t*)take(3 * HCRD_ * 2);
  uint16_t* qT = qkvT, *kT = qkvT + HCRD_, *vT = qkvT + 2 * HCRD_;
  uint16_t* ctxb  = (uint16_t*)take((size_t)NT_ * E_ * 2);
  uint16_t* apb   = (uint16_t*)take((size_t)H_ * C_ * C_ * 2);
  uint16_t* g     = qkvT;          // alias: stage-3 FFN hidden over dead q/k/v
  float*    awb4  = (float*)ctxb;  // alias: 4 split-K partials (12.6 MB) dead before ctxb written
  float*    x1    = (float*)d_out; // alias: inter-stage fp32 activation in output buf

  const dim3 tb32(32, 8);
  const dim3 gEE(E_ / 32, E_ / 32);
  tcvt<<<gEE, tb32, 0, stream>>>(r_wq, wqkv1 + 0 * E_ * E_, E_, E_);
  tcvt<<<gEE, tb32, 0, stream>>>(r_wk, wqkv1 + 1 * E_ * E_, E_, E_);
  tcvt<<<gEE, tb32, 0, stream>>>(r_wv, wqkv1 + 2 * E_ * E_, E_, E_);
  tcvt<<<gEE, tb32, 0, stream>>>(c_wq, wqkv2 + 0 * E_ * E_, E_, E_);
  tcvt<<<gEE, tb32, 0, stream>>>(c_wk, wqkv2 + 1 * E_ * E_, E_, E_);
  tcvt<<<gEE, tb32, 0, stream>>>(c_wv, wqkv2 + 2 * E_ * E_, E_, E_);
  tcvt<<<gEE, tb32, 0, stream>>>(r_wo, rwoT, E_, E_);
  tcvt<<<gEE, tb32, 0, stream>>>(c_wo, cwoT, E_, E_);
  tcvt<<<dim3(F_ / 32, E_ / 32), tb32, 0, stream>>>(f_w1, w1T, E_, F_);  // -> (F,E)
  tcvt<<<dim3(E_ / 32, F_ / 32), tb32, 0, stream>>>(f_w2, w2T, F_, E_);  // -> (E,F)

  const dim3 gProj(E_ / 128, NT_ / 128, 1);
  const dim3 gQKV((3 * E_) / 128, NT_ / 128, 1);

  // ---- stage 1: tied-row attention ----
  ln_k<<<NT_ / 4, 256, 0, stream>>>(x, ln1_s, ln1_b, hb);
  gemm_bt<EP_QKVROW, true, false><<<gQKV, 256, 0, stream>>>(hb, wqkv1, r_bq, r_bk, r_bv, qkvT,
      NT_, 3 * E_, E_, E_, E_, 0, 0, 0.015625f);   // q-scale: D^-.5/sqrt(R)
  gemm_bt<EP_AW, false, false><<<dim3(8, C_ / 128, H_), 256, 0, stream>>>(
      qT, kT, nullptr, nullptr, nullptr, awb4,
      C_, C_, 1024, R_ * D_, R_ * D_, (long)C_ * R_ * D_, (long)C_ * R_ * D_, 1.f);  // split-K=4
  softmax_k4<<<(H_ * C_) / 4, 256, 0, stream>>>(awb4, apb);
  gemm_bt<EP_CTX, false, false><<<dim3((R_ * D_) / 128, C_ / 128, H_), 256, 0, stream>>>(
      apb, vT, nullptr, nullptr, nullptr,
      ctxb, C_, R_ * D_, C_, C_, C_, (long)C_ * C_, (long)R_ * D_ * C_, 1.f);
  gemm_bt<EP_F32B, true, false><<<gProj, 256, 0, stream>>>(ctxb, rwoT, r_bo, nullptr, nullptr, x1,
      NT_, E_, E_, E_, E_, 0, 0, 1.f);

  // ---- stage 2: column attention ----
  ln_k<<<NT_ / 4, 256, 0, stream>>>(x1, ln2_s, ln2_b, hb);
  gemm_bt<EP_QKVCOL, true, true><<<gQKV, 256, 0, stream>>>(hb, wqkv2, c_bq, c_bk, c_bv, qkvT,
      NT_, 3 * E_, E_, E_, E_, 0, 0, 0.125f);      // q-scale: D^-.5
  colattn<<<H_ * C_, 64, 0, stream>>>(qT, kT, vT, ctxb);
  gemm_bt<EP_F32B, true, false><<<gProj, 256, 0, stream>>>(ctxb, cwoT, c_bo, nullptr, nullptr, x1,
      NT_, E_, E_, E_, E_, 0, 0, 1.f);

  // ---- stage 3: FFN ----
  ln_k<<<NT_ / 4, 256, 0, stream>>>(x1, ln3_s, ln3_b, hb);
  gemm_bt<EP_GELU, true, false><<<dim3(F_ / 128, NT_ / 128, 1), 256, 0, stream>>>(
      hb, w1T, f_b1, nullptr, nullptr, g,
      NT_, F_, E_, E_, E_, 0, 0, 1.f);
  gemm_bt<EP_F32B, true, false><<<gProj, 256, 0, stream>>>(g, w2T, f_b2, nullptr, nullptr, d_out,
      NT_, E_, F_, F_, F_, 0, 0, 1.f);
}

// Round 5
// 596.614 us; speedup vs baseline: 1.4232x; 1.0030x over previous
//
#include <hip/hip_runtime.h>
#include <hip/hip_bf16.h>
#include <stdint.h>
#include <stddef.h>

#define R_ 64
#define C_ 256
#define E_ 768
#define H_ 12
#define F_ 3072
#define D_ 64
#define NT_ (R_*C_)   // 16384 tokens
#define HCRD_ ((size_t)H_*C_*R_*D_)

typedef float f32x4 __attribute__((ext_vector_type(4)));
typedef __bf16 bf16x8 __attribute__((ext_vector_type(8)));
typedef unsigned short us4 __attribute__((ext_vector_type(4)));
typedef unsigned short us8 __attribute__((ext_vector_type(8)));

typedef __attribute__((address_space(3))) uint32_t lds_u32;
typedef __attribute__((address_space(1))) uint32_t glb_u32;

__device__ __forceinline__ void gld16(const uint16_t* g, uint16_t* l) {
  // async global->LDS, 16B per lane; LDS dest must be wave-uniform base + lane*16
  __builtin_amdgcn_global_load_lds((const glb_u32*)g, (lds_u32*)l, 16, 0, 0);
}

__device__ __forceinline__ uint16_t f2b(float f) { // fp32 -> bf16, native cvt (RNE)
  __bf16 h = (__bf16)f;
  return *(uint16_t*)&h;
}

#define VM_WAIT4 { asm volatile("s_waitcnt vmcnt(4)" ::: "memory"); __builtin_amdgcn_sched_barrier(0); }
#define VM_WAIT0 { asm volatile("s_waitcnt vmcnt(0)" ::: "memory"); __builtin_amdgcn_sched_barrier(0); }
#define BARRIER  { __builtin_amdgcn_s_barrier(); __builtin_amdgcn_sched_barrier(0); }

// ---------------------------------------------------------------- GEMM
// C(MxN) = A(MxK bf16 rm, row stride lda) * B^T (B NxK bf16 rm, row stride ldb) + epilogue.
// 128x128 tile, BK=32, 256 threads (4 waves, 64x64 each via 4x4 frags of 16x16x32).
// Ring-3 LDS pipeline, counted vmcnt(4) (T4), chunk XOR-swizzle (T2-lite, both-sides),
// setprio around MFMA (T5). Optional XCD-chunked swizzle (SWZ) and A-row PERM.
enum { EP_F32B = 0, EP_GELU = 1, EP_AW = 2, EP_CTX = 3, EP_QKVROW = 4, EP_QKVCOL = 5 };

template<int EP, bool SWZ, bool PERM>
__global__ __launch_bounds__(256)
void gemm_bt(const uint16_t* __restrict__ A, const uint16_t* __restrict__ B,
             const float* __restrict__ bias, const float* __restrict__ biasK,
             const float* __restrict__ biasV, void* __restrict__ out,
             int M, int N, int K, int lda, int ldb, long sAz, long sBz, float scale)
{
  __shared__ uint16_t As[3][4096];   // 3 ring buffers, 128 rows x 32 k (8 KB each)
  __shared__ uint16_t Bs[3][4096];
  const int tid  = threadIdx.x;
  const int wave = tid >> 6, lane = tid & 63;
  const int z = blockIdx.z;

  int bx = blockIdx.x, by = blockIdx.y;
  if constexpr (SWZ) {   // XCD-chunked bijective swizzle (dispatch d -> XCD d%8)
    int lin = blockIdx.x + gridDim.x * blockIdx.y;
    const int q = (gridDim.x * gridDim.y) >> 3;
    const int wid = (lin & 7) * q + (lin >> 3);
    bx = wid % gridDim.x; by = wid / gridDim.x;
  }

  const long bm = (long)by * 128;
  int kc = 0; long bnb = bx;
  if constexpr (EP == EP_AW) { kc = bx & 3; bnb = bx >> 2; }
  const long bn = bnb * 128;
  const uint16_t* Bb = B + (long)z * sBz + bn * (long)ldb + (long)kc * 1024;
  const int wr = (wave >> 1) * 64;
  const int wc = (wave & 1) * 64;
  const int lr = lane & 15;
  const int lq = lane >> 4;

  // staging map: slot t in [0,512): row = t>>2, phys chunk = t&3 (16B per slot).
  // Chunk swizzle: phys chunk c holds global k-chunk c ^ ((row>>1)&3)  -> 2-way banks on read.
  const int t0 = tid, t1 = tid + 256;
  const int ar0 = t0 >> 2, ar1 = t1 >> 2;
  const int ac0 = (((t0 & 3) ^ ((ar0 >> 1) & 3)) * 8);
  const int ac1 = (((t1 & 3) ^ ((ar1 >> 1) & 3)) * 8);

  long am0 = bm + ar0, am1 = bm + ar1;
  if constexpr (PERM) {   // logical row m reads token (m&63)*256 + (m>>6)
    am0 = ((am0 & 63) << 8) | (am0 >> 6);
    am1 = ((am1 & 63) << 8) | (am1 >> 6);
  }
  const uint16_t* a0p = A + (long)z * sAz + am0 * (long)lda + (long)kc * 1024;
  const uint16_t* a1p = A + (long)z * sAz + am1 * (long)lda + (long)kc * 1024;
  const uint16_t* b0p = Bb + (long)ar0 * ldb;
  const uint16_t* b1p = Bb + (long)ar1 * ldb;

  auto STAGE = [&](int bi, int kt) {
    gld16(a0p + kt + ac0, &As[bi][t0 * 8]);
    gld16(a1p + kt + ac1, &As[bi][t1 * 8]);
    gld16(b0p + kt + ac0, &Bs[bi][t0 * 8]);
    gld16(b1p + kt + ac1, &Bs[bi][t1 * 8]);
  };

  // ds_read physical chunk per fragment row (loop-invariant per i)
  int apos[4], bpos[4];
#pragma unroll
  for (int i = 0; i < 4; ++i) {
    const int ra = wr + i * 16 + lr;
    const int rb = wc + i * 16 + lr;
    apos[i] = ra * 32 + (lq ^ ((ra >> 1) & 3)) * 8;
    bpos[i] = rb * 32 + (lq ^ ((rb >> 1) & 3)) * 8;
  }

  f32x4 acc[4][4];
#pragma unroll
  for (int i = 0; i < 4; ++i)
#pragma unroll
    for (int j = 0; j < 4; ++j) acc[i][j] = (f32x4){0.f, 0.f, 0.f, 0.f};

  const int nt = K >> 5;
  // prologue: stage tiles 0 and 1, wait for tile 0 only (counted vmcnt)
  STAGE(0, 0);
  if (nt > 1) { STAGE(1, 32); VM_WAIT4; } else { VM_WAIT0; }
  BARRIER;

  int cur = 0;
  for (int t = 0; t < nt; ++t) {
    if (t + 2 < nt) {                     // issue tile t+2 into the dead slot
      int sl = cur + 2; if (sl >= 3) sl -= 3;
      STAGE(sl, (t + 2) << 5);
    }

    bf16x8 af[4], bfm[4];
#pragma unroll
    for (int i = 0; i < 4; ++i) {
      af[i]  = *(const bf16x8*)&As[cur][apos[i]];
      bfm[i] = *(const bf16x8*)&Bs[cur][bpos[i]];
    }
    __builtin_amdgcn_s_setprio(1);
#pragma unroll
    for (int mi = 0; mi < 4; ++mi)
#pragma unroll
      for (int ni = 0; ni < 4; ++ni)
        acc[mi][ni] = __builtin_amdgcn_mfma_f32_16x16x32_bf16(af[mi], bfm[ni], acc[mi][ni], 0, 0, 0);
    __builtin_amdgcn_s_setprio(0);

    if (t + 2 < nt)      { VM_WAIT4; BARRIER; }   // tile t+1 landed (4 newest still in flight)
    else if (t + 1 < nt) { VM_WAIT0; BARRIER; }   // tail: drain last tile
    cur = (cur == 2) ? 0 : cur + 1;
  }
  __syncthreads();   // protect LDS reuse by slab epilogue

  // ------------------------------------------------------------- epilogue
  if constexpr (EP == EP_F32B) {
#pragma unroll
    for (int mi = 0; mi < 4; ++mi)
#pragma unroll
      for (int ni = 0; ni < 4; ++ni)
#pragma unroll
        for (int r = 0; r < 4; ++r) {
          const long row = bm + wr + mi * 16 + lq * 4 + r;
          const long col = bn + wc + ni * 16 + lr;
          ((float*)out)[row * N + col] = acc[mi][ni][r] + bias[col];
        }
  } else if constexpr (EP == EP_AW) {
#pragma unroll
    for (int mi = 0; mi < 4; ++mi)
#pragma unroll
      for (int ni = 0; ni < 4; ++ni)
#pragma unroll
        for (int r = 0; r < 4; ++r) {
          const long row = bm + wr + mi * 16 + lq * 4 + r;
          const long col = bn + wc + ni * 16 + lr;
          ((float*)out)[((long)(z * 4 + kc) * M + row) * N + col] = acc[mi][ni][r];
        }
  } else if constexpr (EP == EP_CTX) {
#pragma unroll
    for (int mi = 0; mi < 4; ++mi)
#pragma unroll
      for (int ni = 0; ni < 4; ++ni)
#pragma unroll
        for (int r = 0; r < 4; ++r) {
          const long row = bm + wr + mi * 16 + lq * 4 + r;
          const long col = bn + wc + ni * 16 + lr;
          ((uint16_t*)out)[((col >> 6) * C_ + row) * E_ + (long)z * 64 + (col & 63)] =
              f2b(acc[mi][ni][r]);
        }
  } else {
    // slab-based coalesced epilogue (QKVROW / QKVCOL / GELU).
    // Reuse ring buffers (dead after final sync) as 4 wave-private 8 KB slabs.
    uint16_t* slab = (wave < 3) ? &As[wave][0] : &Bs[0][0];
    const long colb = bn + wc;                 // wave tile col base (64-wide)
    int grp = 0; long cc0 = colb;
    const float* bb = bias;
    if constexpr (EP != EP_GELU) {
      grp = colb >= 1536 ? 2 : (colb >= 768 ? 1 : 0);
      cc0 = colb - (long)grp * 768;
      bb = grp == 0 ? bias : (grp == 1 ? biasK : biasV);
    }
    const bool tr = (EP != EP_GELU) && (grp == 2);   // V dumps transposed [d][tok]

    // dump 64x64 tile into slab (bf16)
#pragma unroll
    for (int mi = 0; mi < 4; ++mi)
#pragma unroll
      for (int ni = 0; ni < 4; ++ni)
#pragma unroll
        for (int r = 0; r < 4; ++r) {
          const int lrow = mi * 16 + lq * 4 + r;
          const int lcol = ni * 16 + lr;
          float val;
          if constexpr (EP == EP_GELU) {
            const float t = acc[mi][ni][r] + bias[colb + lcol];
            const float u = 0.7978845608028654f * (t + 0.044715f * t * t * t);
            const float e = __expf(2.f * u);
            val = 0.5f * t * (2.f - 2.f / (e + 1.f));   // t*(1+tanh(u)) inf-safe
          } else {
            val = acc[mi][ni][r] + bb[cc0 + lcol];
            if (grp == 0) val *= scale;
          }
          const int sr = tr ? lcol : lrow;
          const int sc = tr ? lrow : lcol;
          const int psc = (sc & 7) | ((((sc >> 3) ^ (sr & 7))) << 3);
          slab[sr * 64 + psc] = f2b(val);
        }

    // destination base / row stride (wave-uniform)
    uint16_t* o16 = (uint16_t*)out;
    long obase, rstride;
    if constexpr (EP == EP_GELU) {
      obase = (bm + wr) * (long)N + colb; rstride = N;
    } else {
      const long h = cc0 >> 6;
      const long m0 = bm + wr;
      if constexpr (EP == EP_QKVROW) {     // tile rows = tokens (fixed r, c varies)
        const long rr = m0 >> 8, c0 = m0 & 255;
        if (grp < 2) { obase = (size_t)grp * HCRD_ + ((h * C_ + c0) * R_ + rr) * D_; rstride = R_ * D_; }
        else         { obase = 2 * HCRD_ + ((h * R_ + rr) * D_) * C_ + c0;           rstride = C_; }
      } else {                             // QKVCOL: tile rows = r (fixed c)
        const long cq = m0 >> 6;
        if (grp < 2) { obase = (size_t)grp * HCRD_ + ((h * C_ + cq) * R_) * D_; rstride = D_; }
        else         { obase = 2 * HCRD_ + ((h * C_ + cq) * D_) * R_;           rstride = R_; }
      }
    }

    // readout: 8 passes, 16B per lane, fully coalesced
    const int rl = lane >> 3, chn = lane & 7;
#pragma unroll
    for (int pp = 0; pp < 8; ++pp) {
      const int srow = pp * 8 + rl;
      const int pch = chn ^ (srow & 7);
      us8 wv = *(const us8*)&slab[srow * 64 + pch * 8];
      *(us8*)(o16 + obase + (long)srow * rstride + chn * 8) = wv;
    }
  }
}

// ---------------------------------------------------------------- LayerNorm (fp32 in -> bf16 out)
__global__ __launch_bounds__(256)
void ln_k(const float* __restrict__ x, const float* __restrict__ s, const float* __restrict__ b,
          uint16_t* __restrict__ out)
{
  const int wave = threadIdx.x >> 6, lane = threadIdx.x & 63;
  const long row = (long)blockIdx.x * 4 + wave;
  const float* xr = x + row * E_;
  f32x4 v[3];
  float sum = 0.f, sq = 0.f;
#pragma unroll
  for (int i = 0; i < 3; ++i) {
    v[i] = *(const f32x4*)(xr + (i * 64 + lane) * 4);
#pragma unroll
    for (int j = 0; j < 4; ++j) { sum += v[i][j]; sq += v[i][j] * v[i][j]; }
  }
#pragma unroll
  for (int m = 1; m < 64; m <<= 1) { sum += __shfl_xor(sum, m); sq += __shfl_xor(sq, m); }
  const float mu = sum * (1.f / E_);
  const float var = sq * (1.f / E_) - mu * mu;
  const float rs = rsqrtf(var + 1e-6f);
  uint16_t* orow = out + row * E_;
#pragma unroll
  for (int i = 0; i < 3; ++i) {
    const int e0 = (i * 64 + lane) * 4;
    us4 o;
#pragma unroll
    for (int j = 0; j < 4; ++j) o[j] = f2b((v[i][j] - mu) * rs * s[e0 + j] + b[e0 + j]);
    *(us4*)(orow + e0) = o;
  }
}

// ------------------------------------------------ softmax over 256, summing 4 split-K partials
__global__ __launch_bounds__(256)
void softmax_k4(const float* __restrict__ aw4, uint16_t* __restrict__ ap)
{
  const int wave = threadIdx.x >> 6, lane = threadIdx.x & 63;
  const long row = (long)blockIdx.x * 4 + wave;      // 0..H*C-1
  const long h = row >> 8, i = row & 255;
  f32x4 v = (f32x4){0.f, 0.f, 0.f, 0.f};
#pragma unroll
  for (int kc = 0; kc < 4; ++kc) {
    f32x4 t = *(const f32x4*)(aw4 + (((h * 4 + kc) * C_ + i) * C_) + lane * 4);
#pragma unroll
    for (int j = 0; j < 4; ++j) v[j] += t[j];
  }
  float m = fmaxf(fmaxf(v[0], v[1]), fmaxf(v[2], v[3]));
#pragma unroll
  for (int k = 1; k < 64; k <<= 1) m = fmaxf(m, __shfl_xor(m, k));
  f32x4 e; float s = 0.f;
#pragma unroll
  for (int j = 0; j < 4; ++j) { e[j] = __expf(v[j] - m); s += e[j]; }
#pragma unroll
  for (int k = 1; k < 64; k <<= 1) s += __shfl_xor(s, k);
  const float inv = 1.f / s;
  us4 o;
#pragma unroll
  for (int j = 0; j < 4; ++j) o[j] = f2b(e[j] * inv);
  *(us4*)(ap + row * C_ + lane * 4) = o;
}

// ---------------------------------------------------------------- weight transpose + fp32->bf16
// in: (K,N) fp32 row-major; out: (N,K) bf16 row-major
__global__ __launch_bounds__(256)
void tcvt(const float* __restrict__ in, uint16_t* __restrict__ out, int K, int N)
{
  __shared__ float t[32][33];
  const int tx = threadIdx.x, ty = threadIdx.y;   // block (32,8)
  const long k0 = (long)blockIdx.y * 32, n0 = (long)blockIdx.x * 32;
  for (int i = ty; i < 32; i += 8) t[i][tx] = in[(k0 + i) * N + n0 + tx];
  __syncthreads();
  for (int i = ty; i < 32; i += 8) out[(n0 + i) * K + k0 + tx] = f2b(t[tx][i]);
}

// ---------------------------------------------------------------- fused column attention
// one wave per (h,c): S=Q K^T (64x64), row softmax, ctx = P V. q,k: (H,C,R,D); v: (H,C,D,R)
__global__ __launch_bounds__(64)
void colattn(const uint16_t* __restrict__ q, const uint16_t* __restrict__ k,
             const uint16_t* __restrict__ v, uint16_t* __restrict__ ctx)
{
  __shared__ uint16_t Qs[64 * 64];   // reused for P after S is consumed
  __shared__ uint16_t Ks[64 * 64];
  __shared__ uint16_t Vs[64 * 64];
  const int hc = blockIdx.x;
  const int h = hc >> 8, c = hc & 255;
  const int lane = threadIdx.x;
  const uint16_t* qb = q + (long)hc * (R_ * D_);
  const uint16_t* kb = k + (long)hc * (R_ * D_);
  const uint16_t* vb = v + (long)hc * (D_ * R_);
#pragma unroll
  for (int it = 0; it < 8; ++it) {
    const int o = (it * 64 + lane) * 8;
    gld16(qb + o, &Qs[o]);
    gld16(kb + o, &Ks[o]);
    gld16(vb + o, &Vs[o]);
  }
  asm volatile("s_waitcnt vmcnt(0)" ::: "memory");
  __builtin_amdgcn_sched_barrier(0);

  const int lr = lane & 15, lq = lane >> 4;
  f32x4 acc[4][4];
#pragma unroll
  for (int i = 0; i < 4; ++i)
#pragma unroll
    for (int j = 0; j < 4; ++j) acc[i][j] = (f32x4){0.f, 0.f, 0.f, 0.f};

#pragma unroll
  for (int kt = 0; kt < 2; ++kt) {
    bf16x8 af[4], bfm[4];
#pragma unroll
    for (int i = 0; i < 4; ++i) {
      af[i]  = *(const bf16x8*)&Qs[(i * 16 + lr) * 64 + kt * 32 + lq * 8];
      bfm[i] = *(const bf16x8*)&Ks[(i * 16 + lr) * 64 + kt * 32 + lq * 8];
    }
#pragma unroll
    for (int mi = 0; mi < 4; ++mi)
#pragma unroll
      for (int ni = 0; ni < 4; ++ni)
        acc[mi][ni] = __builtin_amdgcn_mfma_f32_16x16x32_bf16(af[mi], bfm[ni], acc[mi][ni], 0, 0, 0);
  }

  // row softmax: row i = mi*16+lq*4+r spans cols ni*16+lr across the 16-lane group
#pragma unroll
  for (int mi = 0; mi < 4; ++mi) {
#pragma unroll
    for (int r = 0; r < 4; ++r) {
      float mx = fmaxf(fmaxf(acc[mi][0][r], acc[mi][1][r]), fmaxf(acc[mi][2][r], acc[mi][3][r]));
#pragma unroll
      for (int s = 1; s < 16; s <<= 1) mx = fmaxf(mx, __shfl_xor(mx, s));
      float e0 = __expf(acc[mi][0][r] - mx), e1 = __expf(acc[mi][1][r] - mx);
      float e2 = __expf(acc[mi][2][r] - mx), e3 = __expf(acc[mi][3][r] - mx);
      float sum = e0 + e1 + e2 + e3;
#pragma unroll
      for (int s = 1; s < 16; s <<= 1) sum += __shfl_xor(sum, s);
      const float inv = 1.f / sum;
      const int i = mi * 16 + lq * 4 + r;
      Qs[i * 64 +  0 + lr] = f2b(e0 * inv);
      Qs[i * 64 + 16 + lr] = f2b(e1 * inv);
      Qs[i * 64 + 32 + lr] = f2b(e2 * inv);
      Qs[i * 64 + 48 + lr] = f2b(e3 * inv);
    }
  }
  __syncthreads();

  f32x4 o_[4][4];
#pragma unroll
  for (int i = 0; i < 4; ++i)
#pragma unroll
    for (int j = 0; j < 4; ++j) o_[i][j] = (f32x4){0.f, 0.f, 0.f, 0.f};

#pragma unroll
  for (int kt = 0; kt < 2; ++kt) {
    bf16x8 pa[4], vv[4];
#pragma unroll
    for (int i = 0; i < 4; ++i) {
      pa[i] = *(const bf16x8*)&Qs[(i * 16 + lr) * 64 + kt * 32 + lq * 8];
      vv[i] = *(const bf16x8*)&Vs[(i * 16 + lr) * 64 + kt * 32 + lq * 8];
    }
#pragma unroll
    for (int mi = 0; mi < 4; ++mi)
#pragma unroll
      for (int ni = 0; ni < 4; ++ni)
        o_[mi][ni] = __builtin_amdgcn_mfma_f32_16x16x32_bf16(pa[mi], vv[ni], o_[mi][ni], 0, 0, 0);
  }

#pragma unroll
  for (int mi = 0; mi < 4; ++mi)
#pragma unroll
    for (int ni = 0; ni < 4; ++ni)
#pragma unroll
      for (int r = 0; r < 4; ++r) {
        const int i = mi * 16 + lq * 4 + r;
        const int d = ni * 16 + lr;
        ctx[((long)i * C_ + c) * E_ + h * 64 + d] = f2b(o_[mi][ni][r]);
      }
}

// ---------------------------------------------------------------- host launch
extern "C" void kernel_launch(void* const* d_in, const int* in_sizes, int n_in,
                              void* d_out, int out_size, void* d_ws, size_t ws_size,
                              hipStream_t stream)
{
  (void)in_sizes; (void)n_in; (void)out_size; (void)ws_size;
  const float* x     = (const float*)d_in[0];
  const float* ln1_s = (const float*)d_in[1];
  const float* ln1_b = (const float*)d_in[2];
  const float* r_wq  = (const float*)d_in[3];
  const float* r_bq  = (const float*)d_in[4];
  const float* r_wk  = (const float*)d_in[5];
  const float* r_bk  = (const float*)d_in[6];
  const float* r_wv  = (const float*)d_in[7];
  const float* r_bv  = (const float*)d_in[8];
  const float* r_wo  = (const float*)d_in[9];
  const float* r_bo  = (const float*)d_in[10];
  const float* ln2_s = (const float*)d_in[11];
  const float* ln2_b = (const float*)d_in[12];
  const float* c_wq  = (const float*)d_in[13];
  const float* c_bq  = (const float*)d_in[14];
  const float* c_wk  = (const float*)d_in[15];
  const float* c_bk  = (const float*)d_in[16];
  const float* c_wv  = (const float*)d_in[17];
  const float* c_bv  = (const float*)d_in[18];
  const float* c_wo  = (const float*)d_in[19];
  const float* c_bo  = (const float*)d_in[20];
  const float* ln3_s = (const float*)d_in[21];
  const float* ln3_b = (const float*)d_in[22];
  const float* f_w1  = (const float*)d_in[23];
  const float* f_b1  = (const float*)d_in[24];
  const float* f_w2  = (const float*)d_in[25];
  const float* f_b2  = (const float*)d_in[26];

  // ---------- workspace layout (≈139.5 MiB peak; aliasing commented) ----------
  uint8_t* p = (uint8_t*)d_ws;
  auto take = [&p](size_t n) { uint8_t* r = p; p += (n + 255) & ~(size_t)255; return r; };

  uint16_t* wqkv1 = (uint16_t*)take((size_t)3 * E_ * E_ * 2);   // fused QKV wT, stage 1
  uint16_t* wqkv2 = (uint16_t*)take((size_t)3 * E_ * E_ * 2);   // fused QKV wT, stage 2
  uint16_t* rwoT  = (uint16_t*)take((size_t)E_ * E_ * 2);
  uint16_t* cwoT  = (uint16_t*)take((size_t)E_ * E_ * 2);
  uint16_t* w1T   = (uint16_t*)take((size_t)E_ * F_ * 2);       // (F,E)
  uint16_t* w2T   = (uint16_t*)take((size_t)F_ * E_ * 2);       // (E,F)
  uint16_t* hb    = (uint16_t*)take((size_t)NT_ * E_ * 2);
  // qkv slab: 3 x 25.166 MB contiguous; g (NT*F bf16, stage 3) aliases it.
  uint16_t* qkvT  = (uint16_t*)take(3 * HCRD_ * 2);
  uint16_t* qT = qkvT, *kT = qkvT + HCRD_, *vT = qkvT + 2 * HCRD_;
  uint16_t* ctxb  = (uint16_t*)take((size_t)NT_ * E_ * 2);
  uint16_t* apb   = (uint16_t*)take((size_t)H_ * C_ * C_ * 2);
  uint16_t* g     = qkvT;          // alias: stage-3 FFN hidden over dead q/k/v
  float*    awb4  = (float*)ctxb;  // alias: 4 split-K partials (12.6 MB) dead before ctxb written
  float*    x1    = (float*)d_out; // alias: inter-stage fp32 activation in output buf

  const dim3 tb32(32, 8);
  const dim3 gEE(E_ / 32, E_ / 32);
  tcvt<<<gEE, tb32, 0, stream>>>(r_wq, wqkv1 + 0 * E_ * E_, E_, E_);
  tcvt<<<gEE, tb32, 0, stream>>>(r_wk, wqkv1 + 1 * E_ * E_, E_, E_);
  tcvt<<<gEE, tb32, 0, stream>>>(r_wv, wqkv1 + 2 * E_ * E_, E_, E_);
  tcvt<<<gEE, tb32, 0, stream>>>(c_wq, wqkv2 + 0 * E_ * E_, E_, E_);
  tcvt<<<gEE, tb32, 0, stream>>>(c_wk, wqkv2 + 1 * E_ * E_, E_, E_);
  tcvt<<<gEE, tb32, 0, stream>>>(c_wv, wqkv2 + 2 * E_ * E_, E_, E_);
  tcvt<<<gEE, tb32, 0, stream>>>(r_wo, rwoT, E_, E_);
  tcvt<<<gEE, tb32, 0, stream>>>(c_wo, cwoT, E_, E_);
  tcvt<<<dim3(F_ / 32, E_ / 32), tb32, 0, stream>>>(f_w1, w1T, E_, F_);  // -> (F,E)
  tcvt<<<dim3(E_ / 32, F_ / 32), tb32, 0, stream>>>(f_w2, w2T, F_, E_);  // -> (E,F)

  const dim3 gProj(E_ / 128, NT_ / 128, 1);
  const dim3 gQKV((3 * E_) / 128, NT_ / 128, 1);

  // ---- stage 1: tied-row attention ----
  ln_k<<<NT_ / 4, 256, 0, stream>>>(x, ln1_s, ln1_b, hb);
  gemm_bt<EP_QKVROW, true, false><<<gQKV, 256, 0, stream>>>(hb, wqkv1, r_bq, r_bk, r_bv, qkvT,
      NT_, 3 * E_, E_, E_, E_, 0, 0, 0.015625f);   // q-scale: D^-.5/sqrt(R)
  gemm_bt<EP_AW, false, false><<<dim3(8, C_ / 128, H_), 256, 0, stream>>>(
      qT, kT, nullptr, nullptr, nullptr, awb4,
      C_, C_, 1024, R_ * D_, R_ * D_, (long)C_ * R_ * D_, (long)C_ * R_ * D_, 1.f);  // split-K=4
  softmax_k4<<<(H_ * C_) / 4, 256, 0, stream>>>(awb4, apb);
  gemm_bt<EP_CTX, false, false><<<dim3((R_ * D_) / 128, C_ / 128, H_), 256, 0, stream>>>(
      apb, vT, nullptr, nullptr, nullptr,
      ctxb, C_, R_ * D_, C_, C_, C_, (long)C_ * C_, (long)R_ * D_ * C_, 1.f);
  gemm_bt<EP_F32B, true, false><<<gProj, 256, 0, stream>>>(ctxb, rwoT, r_bo, nullptr, nullptr, x1,
      NT_, E_, E_, E_, E_, 0, 0, 1.f);

  // ---- stage 2: column attention ----
  ln_k<<<NT_ / 4, 256, 0, stream>>>(x1, ln2_s, ln2_b, hb);
  gemm_bt<EP_QKVCOL, true, true><<<gQKV, 256, 0, stream>>>(hb, wqkv2, c_bq, c_bk, c_bv, qkvT,
      NT_, 3 * E_, E_, E_, E_, 0, 0, 0.125f);      // q-scale: D^-.5
  colattn<<<H_ * C_, 64, 0, stream>>>(qT, kT, vT, ctxb);
  gemm_bt<EP_F32B, true, false><<<gProj, 256, 0, stream>>>(ctxb, cwoT, c_bo, nullptr, nullptr, x1,
      NT_, E_, E_, E_, E_, 0, 0, 1.f);

  // ---- stage 3: FFN ----
  ln_k<<<NT_ / 4, 256, 0, stream>>>(x1, ln3_s, ln3_b, hb);
  gemm_bt<EP_GELU, true, false><<<dim3(F_ / 128, NT_ / 128, 1), 256, 0, stream>>>(
      hb, w1T, f_b1, nullptr, nullptr, g,
      NT_, F_, E_, E_, E_, 0, 0, 1.f);
  gemm_bt<EP_F32B, true, false><<<gProj, 256, 0, stream>>>(g, w2T, f_b2, nullptr, nullptr, d_out,
      NT_, E_, F_, F_, F_, 0, 0, 1.f);
}

// Round 6
// 574.173 us; speedup vs baseline: 1.4788x; 1.0391x over previous
//
#include <hip/hip_runtime.h>
#include <hip/hip_bf16.h>
#include <stdint.h>
#include <stddef.h>

#define R_ 64
#define C_ 256
#define E_ 768
#define H_ 12
#define F_ 3072
#define D_ 64
#define NT_ (R_*C_)   // 16384 tokens
#define HCRD_ ((size_t)H_*C_*R_*D_)

typedef float f32x4 __attribute__((ext_vector_type(4)));
typedef __bf16 bf16x8 __attribute__((ext_vector_type(8)));
typedef unsigned short us4 __attribute__((ext_vector_type(4)));
typedef unsigned short us8 __attribute__((ext_vector_type(8)));

typedef __attribute__((address_space(3))) uint32_t lds_u32;
typedef __attribute__((address_space(1))) uint32_t glb_u32;

__device__ __forceinline__ void gld16(const uint16_t* g, uint16_t* l) {
  __builtin_amdgcn_global_load_lds((const glb_u32*)g, (lds_u32*)l, 16, 0, 0);
}

__device__ __forceinline__ uint16_t f2b(float f) { // fp32 -> bf16, native cvt (RNE)
  __bf16 h = (__bf16)f;
  return *(uint16_t*)&h;
}

#define VM_WAIT6 { asm volatile("s_waitcnt vmcnt(6)" ::: "memory"); __builtin_amdgcn_sched_barrier(0); }
#define VM_WAIT4 { asm volatile("s_waitcnt vmcnt(4)" ::: "memory"); __builtin_amdgcn_sched_barrier(0); }
#define VM_WAIT0 { asm volatile("s_waitcnt vmcnt(0)" ::: "memory"); __builtin_amdgcn_sched_barrier(0); }
#define BARRIER  { __builtin_amdgcn_s_barrier(); __builtin_amdgcn_sched_barrier(0); }

enum { EP_F32B = 0, EP_GELU = 1, EP_AW = 2, EP_CTX = 3, EP_QKVROW = 4, EP_QKVCOL = 5 };

// ================================================================ 256x256 8-phase GEMM
// C(MxN) = A(MxK bf16 rm) * B^T (B NxK bf16 rm) + epilogue. BK=64, 8 waves (2M x 4N),
// each wave 128x64 via acc[8][4] of 16x16x32. LDS 128KB = 2 dbuf x 4 half-tiles
// {B-kh0, A-kh0, B-kh1, A-kh1} of 16KB. Counted vmcnt(6), stage stream 3 halves ahead.
template<int EP, bool PERM>
__global__ __launch_bounds__(512, 2)
void gemm256(const uint16_t* __restrict__ A, const uint16_t* __restrict__ B,
             const float* __restrict__ bias, const float* __restrict__ biasK,
             const float* __restrict__ biasV, void* __restrict__ out,
             int N, int K, int lda, int ldb, float scale)
{
  __shared__ uint16_t lds[2][4][8192];
  const int tid  = threadIdx.x;
  const int wave = tid >> 6, lane = tid & 63;
  const int wm = wave >> 2, wn = wave & 3;     // 2 M-warps x 4 N-warps
  const int lr = lane & 15, lq = lane >> 4;

  // XCD-chunked bijective block swizzle (grids are %8==0)
  int lin = blockIdx.x + gridDim.x * blockIdx.y;
  const int q8 = (gridDim.x * gridDim.y) >> 3;
  const int wid = (lin & 7) * q8 + (lin >> 3);
  const int bx = wid % gridDim.x, by = wid / gridDim.x;
  const long bm = (long)by * 256, bn = (long)bx * 256;

  // staging precompute: thread covers rows r0 and r0+128 of the 256-row half-tiles,
  // phys chunk tid&3; global chunk pre-swizzled (both-sides XOR, rule #21)
  const int r0 = tid >> 2;                                  // 0..127
  const int csw = (((tid & 3) ^ ((r0 >> 1) & 3)) * 8);      // same for r0+128 (bit6 invariant)
  long am0 = bm + r0, am1 = bm + r0 + 128;
  if constexpr (PERM) {  // logical row m reads token (m&63)*256 + (m>>6)
    am0 = ((am0 & 63) << 8) | (am0 >> 6);
    am1 = ((am1 & 63) << 8) | (am1 >> 6);
  }
  const uint16_t* aR0 = A + am0 * (long)lda + csw;
  const uint16_t* aR1 = A + am1 * (long)lda + csw;
  const uint16_t* bR0 = B + (bn + r0) * (long)ldb + csw;
  const uint16_t* bR1 = B + (bn + r0 + 128) * (long)ldb + csw;

  // half-tile stream: H[s], tile u=s>>2, half j=s&3 in {0:Bkh0, 1:Akh0, 2:Bkh1, 3:Akh1}
  auto stageH = [&](int s) {
    const int u = s >> 2, j = s & 3;
    const int kb = u * 64 + (j >> 1) * 32;
    uint16_t* d = &lds[u & 1][j][0];
    if (j & 1) { gld16(aR0 + kb, d + tid * 8); gld16(aR1 + kb, d + (tid + 512) * 8); }
    else       { gld16(bR0 + kb, d + tid * 8); gld16(bR1 + kb, d + (tid + 512) * 8); }
  };
  // ds_read element offset within a half (row 0..255), inverse chunk swizzle
  auto aoff = [&](int row) { return row * 32 + ((lq ^ ((row >> 1) & 3)) * 8); };

  f32x4 acc[8][4];
#pragma unroll
  for (int i = 0; i < 8; ++i)
#pragma unroll
    for (int j = 0; j < 4; ++j) acc[i][j] = (f32x4){0.f, 0.f, 0.f, 0.f};

  const int nt = K >> 6;   // K-tiles of 64 (nt >= 3 for all uses here)
  // prologue: tile0 complete + tile1 halves 0..2; tile0 landed before loop
  stageH(0); stageH(1); stageH(2); stageH(3);
  VM_WAIT4;
  stageH(4); stageH(5); stageH(6);
  VM_WAIT6;
  BARRIER;

  for (int t = 0; t < nt; ++t) {
    const int buf = t & 1;
    const uint16_t* B0h = &lds[buf][0][0];
    const uint16_t* A0h = &lds[buf][1][0];
    const uint16_t* B1h = &lds[buf][2][0];
    const uint16_t* A1h = &lds[buf][3][0];
    const int s0 = 4 * t + 7;
    bf16x8 af[4], bf[4];

    // ---- phase 0: kh0, mi 0-3 (stages (t+1).Akh1 -> other buffer)
#pragma unroll
    for (int i = 0; i < 4; ++i) {
      bf[i] = *(const bf16x8*)&B0h[aoff(wn * 64 + i * 16 + lr)];
      af[i] = *(const bf16x8*)&A0h[aoff(wm * 128 + i * 16 + lr)];
    }
    if (s0 < 4 * nt) stageH(s0);
    BARRIER;
    __builtin_amdgcn_s_setprio(1);
#pragma unroll
    for (int mi = 0; mi < 4; ++mi)
#pragma unroll
      for (int ni = 0; ni < 4; ++ni)
        acc[mi][ni] = __builtin_amdgcn_mfma_f32_16x16x32_bf16(af[mi], bf[ni], acc[mi][ni], 0, 0, 0);
    __builtin_amdgcn_s_setprio(0);
    BARRIER;

    // ---- phase 1: kh0, mi 4-7 (stages (t+2).Bkh0 -> this buffer; Bkh0 last read ph0)
#pragma unroll
    for (int i = 0; i < 4; ++i)
      af[i] = *(const bf16x8*)&A0h[aoff(wm * 128 + 64 + i * 16 + lr)];
    if (s0 + 1 < 4 * nt) stageH(s0 + 1);
    BARRIER;
    __builtin_amdgcn_s_setprio(1);
#pragma unroll
    for (int mi = 0; mi < 4; ++mi)
#pragma unroll
      for (int ni = 0; ni < 4; ++ni)
        acc[4 + mi][ni] = __builtin_amdgcn_mfma_f32_16x16x32_bf16(af[mi], bf[ni], acc[4 + mi][ni], 0, 0, 0);
    __builtin_amdgcn_s_setprio(0);
    BARRIER;

    // ---- phase 2: kh1, mi 0-3 (stages (t+2).Akh0; Akh0 last read ph1)
#pragma unroll
    for (int i = 0; i < 4; ++i) {
      bf[i] = *(const bf16x8*)&B1h[aoff(wn * 64 + i * 16 + lr)];
      af[i] = *(const bf16x8*)&A1h[aoff(wm * 128 + i * 16 + lr)];
    }
    if (s0 + 2 < 4 * nt) stageH(s0 + 2);
    BARRIER;
    __builtin_amdgcn_s_setprio(1);
#pragma unroll
    for (int mi = 0; mi < 4; ++mi)
#pragma unroll
      for (int ni = 0; ni < 4; ++ni)
        acc[mi][ni] = __builtin_amdgcn_mfma_f32_16x16x32_bf16(af[mi], bf[ni], acc[mi][ni], 0, 0, 0);
    __builtin_amdgcn_s_setprio(0);
    BARRIER;

    // ---- phase 3: kh1, mi 4-7 (stages (t+2).Bkh1; Bkh1 last read ph2) + per-tile vmcnt
#pragma unroll
    for (int i = 0; i < 4; ++i)
      af[i] = *(const bf16x8*)&A1h[aoff(wm * 128 + 64 + i * 16 + lr)];
    if (s0 + 3 < 4 * nt) stageH(s0 + 3);
    BARRIER;
    __builtin_amdgcn_s_setprio(1);
#pragma unroll
    for (int mi = 0; mi < 4; ++mi)
#pragma unroll
      for (int ni = 0; ni < 4; ++ni)
        acc[4 + mi][ni] = __builtin_amdgcn_mfma_f32_16x16x32_bf16(af[mi], bf[ni], acc[4 + mi][ni], 0, 0, 0);
    __builtin_amdgcn_s_setprio(0);
    if (t < nt - 2)       VM_WAIT6       // tile t+1 fully landed, newest 3 halves in flight
    else if (t == nt - 2) VM_WAIT0       // drain: nothing outstanding entering last tile
    BARRIER;
  }
  __syncthreads();

  // ------------------------------------------------------------- epilogue
  if constexpr (EP == EP_F32B) {
#pragma unroll
    for (int mi = 0; mi < 8; ++mi)
#pragma unroll
      for (int ni = 0; ni < 4; ++ni)
#pragma unroll
        for (int r = 0; r < 4; ++r) {
          const long row = bm + wm * 128 + mi * 16 + lq * 4 + r;
          const long col = bn + wn * 64 + ni * 16 + lr;
          ((float*)out)[row * N + col] = acc[mi][ni][r] + bias[col];
        }
  } else {
    // slab epilogue: wave-private 16KB (2 sub-tiles of 64x64), coalesced 16B stores
    uint16_t* slabW = ((uint16_t*)lds) + (size_t)wave * 8192;
    const long colb = bn + wn * 64;
    int grp = 0; long cc0 = colb;
    const float* bb = bias;
    if constexpr (EP != EP_GELU) {
      grp = colb >= 1536 ? 2 : (colb >= 768 ? 1 : 0);
      cc0 = colb - (long)grp * 768;
      bb = grp == 0 ? bias : (grp == 1 ? biasK : biasV);
    }
    const bool tr = (EP != EP_GELU) && (grp == 2);
#pragma unroll
    for (int sub = 0; sub < 2; ++sub) {
      uint16_t* slab = slabW + sub * 4096;
      const long m0 = bm + wm * 128 + sub * 64;
#pragma unroll
      for (int mi = 0; mi < 4; ++mi)
#pragma unroll
        for (int ni = 0; ni < 4; ++ni)
#pragma unroll
          for (int r = 0; r < 4; ++r) {
            const int lrow = mi * 16 + lq * 4 + r;
            const int lcol = ni * 16 + lr;
            float val;
            if constexpr (EP == EP_GELU) {
              const float t = acc[sub * 4 + mi][ni][r] + bias[colb + lcol];
              const float u = 0.7978845608028654f * (t + 0.044715f * t * t * t);
              const float e = __expf(2.f * u);
              val = 0.5f * t * (2.f - 2.f / (e + 1.f));
            } else {
              val = acc[sub * 4 + mi][ni][r] + bb[cc0 + lcol];
              if (grp == 0) val *= scale;
            }
            const int sr = tr ? lcol : lrow;
            const int sc = tr ? lrow : lcol;
            const int psc = (sc & 7) | ((((sc >> 3) ^ (sr & 7))) << 3);
            slab[sr * 64 + psc] = f2b(val);
          }
      uint16_t* o16 = (uint16_t*)out;
      long obase, rstride;
      if constexpr (EP == EP_GELU) {
        obase = m0 * (long)N + colb; rstride = N;
      } else {
        const long h = cc0 >> 6;
        if constexpr (EP == EP_QKVROW) {   // tile rows = tokens (fixed r, c varies)
          const long rr = m0 >> 8, c0 = m0 & 255;
          if (grp < 2) { obase = (size_t)grp * HCRD_ + ((h * C_ + c0) * R_ + rr) * D_; rstride = R_ * D_; }
          else         { obase = 2 * HCRD_ + ((h * R_ + rr) * D_) * C_ + c0;           rstride = C_; }
        } else {                           // QKVCOL: tile rows = r (fixed c)
          const long cq = m0 >> 6;
          if (grp < 2) { obase = (size_t)grp * HCRD_ + ((h * C_ + cq) * R_) * D_; rstride = D_; }
          else         { obase = 2 * HCRD_ + ((h * C_ + cq) * D_) * R_;           rstride = R_; }
        }
      }
      const int rl = lane >> 3, chn = lane & 7;
#pragma unroll
      for (int pp = 0; pp < 8; ++pp) {
        const int srow = pp * 8 + rl;
        const int pch = chn ^ (srow & 7);
        us8 wv = *(const us8*)&slab[srow * 64 + pch * 8];
        *(us8*)(o16 + obase + (long)srow * rstride + chn * 8) = wv;
      }
    }
  }
}

// ================================================================ 128x128 GEMM (AW / CTX only)
template<int EP>
__global__ __launch_bounds__(256)
void gemm_bt(const uint16_t* __restrict__ A, const uint16_t* __restrict__ B,
             void* __restrict__ out,
             int M, int N, int K, int lda, int ldb, long sAz, long sBz)
{
  __shared__ uint16_t As[3][4096];
  __shared__ uint16_t Bs[3][4096];
  const int tid  = threadIdx.x;
  const int wave = tid >> 6, lane = tid & 63;
  const int z = blockIdx.z;

  const long bm = (long)blockIdx.y * 128;
  int kc = 0; long bnb = blockIdx.x;
  if constexpr (EP == EP_AW) { kc = blockIdx.x & 3; bnb = blockIdx.x >> 2; }
  const long bn = bnb * 128;
  const int wr = (wave >> 1) * 64;
  const int wc = (wave & 1) * 64;
  const int lr = lane & 15;
  const int lq = lane >> 4;

  const int t0 = tid, t1 = tid + 256;
  const int ar0 = t0 >> 2, ar1 = t1 >> 2;
  const int ac0 = (((t0 & 3) ^ ((ar0 >> 1) & 3)) * 8);
  const int ac1 = (((t1 & 3) ^ ((ar1 >> 1) & 3)) * 8);

  const uint16_t* a0p = A + (long)z * sAz + (bm + ar0) * (long)lda + (long)kc * 1024;
  const uint16_t* a1p = A + (long)z * sAz + (bm + ar1) * (long)lda + (long)kc * 1024;
  const uint16_t* b0p = B + (long)z * sBz + (bn + ar0) * (long)ldb + (long)kc * 1024;
  const uint16_t* b1p = B + (long)z * sBz + (bn + ar1) * (long)ldb + (long)kc * 1024;

  auto STAGE = [&](int bi, int kt) {
    gld16(a0p + kt + ac0, &As[bi][t0 * 8]);
    gld16(a1p + kt + ac1, &As[bi][t1 * 8]);
    gld16(b0p + kt + ac0, &Bs[bi][t0 * 8]);
    gld16(b1p + kt + ac1, &Bs[bi][t1 * 8]);
  };

  int apos[4], bpos[4];
#pragma unroll
  for (int i = 0; i < 4; ++i) {
    const int ra = wr + i * 16 + lr;
    const int rb = wc + i * 16 + lr;
    apos[i] = ra * 32 + (lq ^ ((ra >> 1) & 3)) * 8;
    bpos[i] = rb * 32 + (lq ^ ((rb >> 1) & 3)) * 8;
  }

  f32x4 acc[4][4];
#pragma unroll
  for (int i = 0; i < 4; ++i)
#pragma unroll
    for (int j = 0; j < 4; ++j) acc[i][j] = (f32x4){0.f, 0.f, 0.f, 0.f};

  const int nt = K >> 5;
  STAGE(0, 0);
  if (nt > 1) { STAGE(1, 32); VM_WAIT4; } else { VM_WAIT0; }
  BARRIER;

  int cur = 0;
  for (int t = 0; t < nt; ++t) {
    if (t + 2 < nt) {
      int sl = cur + 2; if (sl >= 3) sl -= 3;
      STAGE(sl, (t + 2) << 5);
    }
    bf16x8 af[4], bfm[4];
#pragma unroll
    for (int i = 0; i < 4; ++i) {
      af[i]  = *(const bf16x8*)&As[cur][apos[i]];
      bfm[i] = *(const bf16x8*)&Bs[cur][bpos[i]];
    }
    __builtin_amdgcn_s_setprio(1);
#pragma unroll
    for (int mi = 0; mi < 4; ++mi)
#pragma unroll
      for (int ni = 0; ni < 4; ++ni)
        acc[mi][ni] = __builtin_amdgcn_mfma_f32_16x16x32_bf16(af[mi], bfm[ni], acc[mi][ni], 0, 0, 0);
    __builtin_amdgcn_s_setprio(0);

    if (t + 2 < nt)      { VM_WAIT4; BARRIER; }
    else if (t + 1 < nt) { VM_WAIT0; BARRIER; }
    cur = (cur == 2) ? 0 : cur + 1;
  }

#pragma unroll
  for (int mi = 0; mi < 4; ++mi)
#pragma unroll
    for (int ni = 0; ni < 4; ++ni)
#pragma unroll
      for (int r = 0; r < 4; ++r) {
        const long row = bm + wr + mi * 16 + lq * 4 + r;
        const long col = bn + wc + ni * 16 + lr;
        if constexpr (EP == EP_AW) {
          ((float*)out)[((long)(z * 4 + kc) * M + row) * N + col] = acc[mi][ni][r];
        } else {  // EP_CTX
          ((uint16_t*)out)[((col >> 6) * C_ + row) * E_ + (long)z * 64 + (col & 63)] =
              f2b(acc[mi][ni][r]);
        }
      }
}

// ---------------------------------------------------------------- LayerNorm (fp32 in -> bf16 out)
__global__ __launch_bounds__(256)
void ln_k(const float* __restrict__ x, const float* __restrict__ s, const float* __restrict__ b,
          uint16_t* __restrict__ out)
{
  const int wave = threadIdx.x >> 6, lane = threadIdx.x & 63;
  const long row = (long)blockIdx.x * 4 + wave;
  const float* xr = x + row * E_;
  f32x4 v[3];
  float sum = 0.f, sq = 0.f;
#pragma unroll
  for (int i = 0; i < 3; ++i) {
    v[i] = *(const f32x4*)(xr + (i * 64 + lane) * 4);
#pragma unroll
    for (int j = 0; j < 4; ++j) { sum += v[i][j]; sq += v[i][j] * v[i][j]; }
  }
#pragma unroll
  for (int m = 1; m < 64; m <<= 1) { sum += __shfl_xor(sum, m); sq += __shfl_xor(sq, m); }
  const float mu = sum * (1.f / E_);
  const float var = sq * (1.f / E_) - mu * mu;
  const float rs = rsqrtf(var + 1e-6f);
  uint16_t* orow = out + row * E_;
#pragma unroll
  for (int i = 0; i < 3; ++i) {
    const int e0 = (i * 64 + lane) * 4;
    us4 o;
#pragma unroll
    for (int j = 0; j < 4; ++j) o[j] = f2b((v[i][j] - mu) * rs * s[e0 + j] + b[e0 + j]);
    *(us4*)(orow + e0) = o;
  }
}

// ------------------------------------------------ softmax over 256, summing 4 split-K partials
__global__ __launch_bounds__(256)
void softmax_k4(const float* __restrict__ aw4, uint16_t* __restrict__ ap)
{
  const int wave = threadIdx.x >> 6, lane = threadIdx.x & 63;
  const long row = (long)blockIdx.x * 4 + wave;
  const long h = row >> 8, i = row & 255;
  f32x4 v = (f32x4){0.f, 0.f, 0.f, 0.f};
#pragma unroll
  for (int kc = 0; kc < 4; ++kc) {
    f32x4 t = *(const f32x4*)(aw4 + (((h * 4 + kc) * C_ + i) * C_) + lane * 4);
#pragma unroll
    for (int j = 0; j < 4; ++j) v[j] += t[j];
  }
  float m = fmaxf(fmaxf(v[0], v[1]), fmaxf(v[2], v[3]));
#pragma unroll
  for (int k = 1; k < 64; k <<= 1) m = fmaxf(m, __shfl_xor(m, k));
  f32x4 e; float s = 0.f;
#pragma unroll
  for (int j = 0; j < 4; ++j) { e[j] = __expf(v[j] - m); s += e[j]; }
#pragma unroll
  for (int k = 1; k < 64; k <<= 1) s += __shfl_xor(s, k);
  const float inv = 1.f / s;
  us4 o;
#pragma unroll
  for (int j = 0; j < 4; ++j) o[j] = f2b(e[j] * inv);
  *(us4*)(ap + row * C_ + lane * 4) = o;
}

// ---------------------------------------------------------------- weight transpose + fp32->bf16
__global__ __launch_bounds__(256)
void tcvt(const float* __restrict__ in, uint16_t* __restrict__ out, int K, int N)
{
  __shared__ float t[32][33];
  const int tx = threadIdx.x, ty = threadIdx.y;   // block (32,8)
  const long k0 = (long)blockIdx.y * 32, n0 = (long)blockIdx.x * 32;
  for (int i = ty; i < 32; i += 8) t[i][tx] = in[(k0 + i) * N + n0 + tx];
  __syncthreads();
  for (int i = ty; i < 32; i += 8) out[(n0 + i) * K + k0 + tx] = f2b(t[tx][i]);
}

// ---------------------------------------------------------------- fused column attention
__global__ __launch_bounds__(64)
void colattn(const uint16_t* __restrict__ q, const uint16_t* __restrict__ k,
             const uint16_t* __restrict__ v, uint16_t* __restrict__ ctx)
{
  __shared__ uint16_t Qs[64 * 64];
  __shared__ uint16_t Ks[64 * 64];
  __shared__ uint16_t Vs[64 * 64];
  const int hc = blockIdx.x;
  const int h = hc >> 8, c = hc & 255;
  const int lane = threadIdx.x;
  const uint16_t* qb = q + (long)hc * (R_ * D_);
  const uint16_t* kb = k + (long)hc * (R_ * D_);
  const uint16_t* vb = v + (long)hc * (D_ * R_);
#pragma unroll
  for (int it = 0; it < 8; ++it) {
    const int o = (it * 64 + lane) * 8;
    gld16(qb + o, &Qs[o]);
    gld16(kb + o, &Ks[o]);
    gld16(vb + o, &Vs[o]);
  }
  asm volatile("s_waitcnt vmcnt(0)" ::: "memory");
  __builtin_amdgcn_sched_barrier(0);

  const int lr = lane & 15, lq = lane >> 4;
  f32x4 acc[4][4];
#pragma unroll
  for (int i = 0; i < 4; ++i)
#pragma unroll
    for (int j = 0; j < 4; ++j) acc[i][j] = (f32x4){0.f, 0.f, 0.f, 0.f};

#pragma unroll
  for (int kt = 0; kt < 2; ++kt) {
    bf16x8 af[4], bfm[4];
#pragma unroll
    for (int i = 0; i < 4; ++i) {
      af[i]  = *(const bf16x8*)&Qs[(i * 16 + lr) * 64 + kt * 32 + lq * 8];
      bfm[i] = *(const bf16x8*)&Ks[(i * 16 + lr) * 64 + kt * 32 + lq * 8];
    }
#pragma unroll
    for (int mi = 0; mi < 4; ++mi)
#pragma unroll
      for (int ni = 0; ni < 4; ++ni)
        acc[mi][ni] = __builtin_amdgcn_mfma_f32_16x16x32_bf16(af[mi], bfm[ni], acc[mi][ni], 0, 0, 0);
  }

#pragma unroll
  for (int mi = 0; mi < 4; ++mi) {
#pragma unroll
    for (int r = 0; r < 4; ++r) {
      float mx = fmaxf(fmaxf(acc[mi][0][r], acc[mi][1][r]), fmaxf(acc[mi][2][r], acc[mi][3][r]));
#pragma unroll
      for (int s = 1; s < 16; s <<= 1) mx = fmaxf(mx, __shfl_xor(mx, s));
      float e0 = __expf(acc[mi][0][r] - mx), e1 = __expf(acc[mi][1][r] - mx);
      float e2 = __expf(acc[mi][2][r] - mx), e3 = __expf(acc[mi][3][r] - mx);
      float sum = e0 + e1 + e2 + e3;
#pragma unroll
      for (int s = 1; s < 16; s <<= 1) sum += __shfl_xor(sum, s);
      const float inv = 1.f / sum;
      const int i = mi * 16 + lq * 4 + r;
      Qs[i * 64 +  0 + lr] = f2b(e0 * inv);
      Qs[i * 64 + 16 + lr] = f2b(e1 * inv);
      Qs[i * 64 + 32 + lr] = f2b(e2 * inv);
      Qs[i * 64 + 48 + lr] = f2b(e3 * inv);
    }
  }
  __syncthreads();

  f32x4 o_[4][4];
#pragma unroll
  for (int i = 0; i < 4; ++i)
#pragma unroll
    for (int j = 0; j < 4; ++j) o_[i][j] = (f32x4){0.f, 0.f, 0.f, 0.f};

#pragma unroll
  for (int kt = 0; kt < 2; ++kt) {
    bf16x8 pa[4], vv[4];
#pragma unroll
    for (int i = 0; i < 4; ++i) {
      pa[i] = *(const bf16x8*)&Qs[(i * 16 + lr) * 64 + kt * 32 + lq * 8];
      vv[i] = *(const bf16x8*)&Vs[(i * 16 + lr) * 64 + kt * 32 + lq * 8];
    }
#pragma unroll
    for (int mi = 0; mi < 4; ++mi)
#pragma unroll
      for (int ni = 0; ni < 4; ++ni)
        o_[mi][ni] = __builtin_amdgcn_mfma_f32_16x16x32_bf16(pa[mi], vv[ni], o_[mi][ni], 0, 0, 0);
  }

#pragma unroll
  for (int mi = 0; mi < 4; ++mi)
#pragma unroll
    for (int ni = 0; ni < 4; ++ni)
#pragma unroll
      for (int r = 0; r < 4; ++r) {
        const int i = mi * 16 + lq * 4 + r;
        const int d = ni * 16 + lr;
        ctx[((long)i * C_ + c) * E_ + h * 64 + d] = f2b(o_[mi][ni][r]);
      }
}

// ---------------------------------------------------------------- host launch
extern "C" void kernel_launch(void* const* d_in, const int* in_sizes, int n_in,
                              void* d_out, int out_size, void* d_ws, size_t ws_size,
                              hipStream_t stream)
{
  (void)in_sizes; (void)n_in; (void)out_size; (void)ws_size;
  const float* x     = (const float*)d_in[0];
  const float* ln1_s = (const float*)d_in[1];
  const float* ln1_b = (const float*)d_in[2];
  const float* r_wq  = (const float*)d_in[3];
  const float* r_bq  = (const float*)d_in[4];
  const float* r_wk  = (const float*)d_in[5];
  const float* r_bk  = (const float*)d_in[6];
  const float* r_wv  = (const float*)d_in[7];
  const float* r_bv  = (const float*)d_in[8];
  const float* r_wo  = (const float*)d_in[9];
  const float* r_bo  = (const float*)d_in[10];
  const float* ln2_s = (const float*)d_in[11];
  const float* ln2_b = (const float*)d_in[12];
  const float* c_wq  = (const float*)d_in[13];
  const float* c_bq  = (const float*)d_in[14];
  const float* c_wk  = (const float*)d_in[15];
  const float* c_bk  = (const float*)d_in[16];
  const float* c_wv  = (const float*)d_in[17];
  const float* c_bv  = (const float*)d_in[18];
  const float* c_wo  = (const float*)d_in[19];
  const float* c_bo  = (const float*)d_in[20];
  const float* ln3_s = (const float*)d_in[21];
  const float* ln3_b = (const float*)d_in[22];
  const float* f_w1  = (const float*)d_in[23];
  const float* f_b1  = (const float*)d_in[24];
  const float* f_w2  = (const float*)d_in[25];
  const float* f_b2  = (const float*)d_in[26];

  uint8_t* p = (uint8_t*)d_ws;
  auto take = [&p](size_t n) { uint8_t* r = p; p += (n + 255) & ~(size_t)255; return r; };

  uint16_t* wqkv1 = (uint16_t*)take((size_t)3 * E_ * E_ * 2);
  uint16_t* wqkv2 = (uint16_t*)take((size_t)3 * E_ * E_ * 2);
  uint16_t* rwoT  = (uint16_t*)take((size_t)E_ * E_ * 2);
  uint16_t* cwoT  = (uint16_t*)take((size_t)E_ * E_ * 2);
  uint16_t* w1T   = (uint16_t*)take((size_t)E_ * F_ * 2);
  uint16_t* w2T   = (uint16_t*)take((size_t)F_ * E_ * 2);
  uint16_t* hb    = (uint16_t*)take((size_t)NT_ * E_ * 2);
  uint16_t* qkvT  = (uint16_t*)take(3 * HCRD_ * 2);
  uint16_t* qT = qkvT, *kT = qkvT + HCRD_, *vT = qkvT + 2 * HCRD_;
  uint16_t* ctxb  = (uint16_t*)take((size_t)NT_ * E_ * 2);
  uint16_t* apb   = (uint16_t*)take((size_t)H_ * C_ * C_ * 2);
  uint16_t* g     = qkvT;          // alias: stage-3 FFN hidden over dead q/k/v
  float*    awb4  = (float*)ctxb;  // alias: split-K partials dead before ctxb written
  float*    x1    = (float*)d_out; // alias: inter-stage fp32 activation in output buf

  const dim3 tb32(32, 8);
  const dim3 gEE(E_ / 32, E_ / 32);
  tcvt<<<gEE, tb32, 0, stream>>>(r_wq, wqkv1 + 0 * E_ * E_, E_, E_);
  tcvt<<<gEE, tb32, 0, stream>>>(r_wk, wqkv1 + 1 * E_ * E_, E_, E_);
  tcvt<<<gEE, tb32, 0, stream>>>(r_wv, wqkv1 + 2 * E_ * E_, E_, E_);
  tcvt<<<gEE, tb32, 0, stream>>>(c_wq, wqkv2 + 0 * E_ * E_, E_, E_);
  tcvt<<<gEE, tb32, 0, stream>>>(c_wk, wqkv2 + 1 * E_ * E_, E_, E_);
  tcvt<<<gEE, tb32, 0, stream>>>(c_wv, wqkv2 + 2 * E_ * E_, E_, E_);
  tcvt<<<gEE, tb32, 0, stream>>>(r_wo, rwoT, E_, E_);
  tcvt<<<gEE, tb32, 0, stream>>>(c_wo, cwoT, E_, E_);
  tcvt<<<dim3(F_ / 32, E_ / 32), tb32, 0, stream>>>(f_w1, w1T, E_, F_);
  tcvt<<<dim3(E_ / 32, F_ / 32), tb32, 0, stream>>>(f_w2, w2T, F_, E_);

  // ---- stage 1: tied-row attention ----
  ln_k<<<NT_ / 4, 256, 0, stream>>>(x, ln1_s, ln1_b, hb);
  gemm256<EP_QKVROW, false><<<dim3(9, 64), 512, 0, stream>>>(
      hb, wqkv1, r_bq, r_bk, r_bv, qkvT, 3 * E_, E_, E_, E_, 0.015625f);
  gemm_bt<EP_AW><<<dim3(8, 2, H_), 256, 0, stream>>>(
      qT, kT, awb4, C_, C_, 1024, R_ * D_, R_ * D_, (long)C_ * R_ * D_, (long)C_ * R_ * D_);
  softmax_k4<<<(H_ * C_) / 4, 256, 0, stream>>>(awb4, apb);
  gemm_bt<EP_CTX><<<dim3((R_ * D_) / 128, 2, H_), 256, 0, stream>>>(
      apb, vT, ctxb, C_, R_ * D_, C_, C_, C_, (long)C_ * C_, (long)R_ * D_ * C_);
  gemm256<EP_F32B, false><<<dim3(3, 64), 512, 0, stream>>>(
      ctxb, rwoT, r_bo, nullptr, nullptr, x1, E_, E_, E_, E_, 1.f);

  // ---- stage 2: column attention ----
  ln_k<<<NT_ / 4, 256, 0, stream>>>(x1, ln2_s, ln2_b, hb);
  gemm256<EP_QKVCOL, true><<<dim3(9, 64), 512, 0, stream>>>(
      hb, wqkv2, c_bq, c_bk, c_bv, qkvT, 3 * E_, E_, E_, E_, 0.125f);
  colattn<<<H_ * C_, 64, 0, stream>>>(qT, kT, vT, ctxb);
  gemm256<EP_F32B, false><<<dim3(3, 64), 512, 0, stream>>>(
      ctxb, cwoT, c_bo, nullptr, nullptr, x1, E_, E_, E_, E_, 1.f);

  // ---- stage 3: FFN ----
  ln_k<<<NT_ / 4, 256, 0, stream>>>(x1, ln3_s, ln3_b, hb);
  gemm256<EP_GELU, false><<<dim3(12, 64), 512, 0, stream>>>(
      hb, w1T, f_b1, nullptr, nullptr, g, F_, E_, E_, E_, 1.f);
  gemm256<EP_F32B, false><<<dim3(3, 64), 512, 0, stream>>>(
      g, w2T, f_b2, nullptr, nullptr, d_out, E_, F_, F_, F_, 1.f);
}